// Round 26
// baseline (250.175 us; speedup 1.0000x reference)
//
#include <hip/hip_runtime.h>
#include <hip/hip_bf16.h>

// RGCN 2-layer forward. Transform-then-aggregate on BOTH layers.
// L1: Y[n,0:1152] = bf16(x[n]) @ [W_r0..W_r7 | Wroot]  (dense bf16 MFMA GEMM,
//     operand-swapped). THIS ROUND: 9 chunks as a #pragma unroll 1 LOOP of
//     3 iters x 3 chunks (period-3 triple-buffer rotation) -> ~1/3 code size,
//     fits 32KB L1I (I-cache-miss theory for the 100us plateau).
// Sort: counting sort -> ei2[pos] = {src*8+rel, bits(1/cnt)} (mean folded/edge).
// hgather: quarter-wave per node (16 lanes x 8 cols, uint4), 8-deep pipeline;
//     fused layer-2 transform -> t[n,0:18].
// out2: 8 lanes/node (lane=relation), scale pre-folded.

#define NR 8
#define DH 128

typedef short short8 __attribute__((ext_vector_type(8)));
typedef float f32x4 __attribute__((ext_vector_type(4)));

__device__ inline ushort f2bf(float v) {
  __hip_bfloat16 b = __float2bfloat16(v);
  return *reinterpret_cast<ushort*>(&b);
}
__device__ inline float bf2f(ushort u) {
  __hip_bfloat16 b;
  *reinterpret_cast<ushort*>(&b) = u;
  return __bfloat162float(b);
}
__device__ inline uint pk2(float lo, float hi) {
  return (uint)f2bf(lo) | ((uint)f2bf(hi) << 16);
}
union U128 { uint4 u; short8 s; };
union FU { float f; int i; };

// ---------- counting sort ----------
__global__ __launch_bounds__(256) void k_hist(const int* __restrict__ dst, const int* __restrict__ et,
                                              int* __restrict__ hist, int E) {
  int e = blockIdx.x * 256 + threadIdx.x;
  if (e < E) atomicAdd(&hist[dst[e] * NR + et[e]], 1);
}

__global__ __launch_bounds__(256) void k_scan_local(const int* __restrict__ hist, int* __restrict__ offs,
                                                    int* __restrict__ blksum, int S) {
  __shared__ int tsum[256];
  int tid = threadIdx.x;
  int base = blockIdx.x * 1024 + tid * 4;
  int v[4], tot = 0;
  #pragma unroll
  for (int i = 0; i < 4; i++) { v[i] = (base + i < S) ? hist[base + i] : 0; tot += v[i]; }
  tsum[tid] = tot;
  __syncthreads();
  for (int off = 1; off < 256; off <<= 1) {
    int val = tsum[tid];
    int add = (tid >= off) ? tsum[tid - off] : 0;
    __syncthreads();
    tsum[tid] = val + add;
    __syncthreads();
  }
  int run = tsum[tid] - tot;
  #pragma unroll
  for (int i = 0; i < 4; i++) {
    if (base + i < S) offs[base + i] = run;
    run += v[i];
  }
  if (tid == 255) blksum[blockIdx.x] = tsum[255];
}

__global__ __launch_bounds__(512) void k_scan_blk(const int* __restrict__ blksum, int* __restrict__ blkoff, int NB) {
  __shared__ int s[512];
  int tid = threadIdx.x;
  int v = (tid < NB) ? blksum[tid] : 0;
  s[tid] = v;
  __syncthreads();
  for (int off = 1; off < 512; off <<= 1) {
    int val = s[tid];
    int add = (tid >= off) ? s[tid - off] : 0;
    __syncthreads();
    s[tid] = val + add;
    __syncthreads();
  }
  if (tid < NB) blkoff[tid] = s[tid] - v;
}

__global__ __launch_bounds__(256) void k_scan_add(int* __restrict__ offs, const int* __restrict__ blkoff, int S) {
  int tid = threadIdx.x;
  int base = blockIdx.x * 1024 + tid * 4;
  int add = blkoff[blockIdx.x];
  #pragma unroll
  for (int i = 0; i < 4; i++)
    if (base + i < S) offs[base + i] += add;
}

// scatter: ei2[pos] = {src*8+rel, bits(1/cnt)}; offs[seg] becomes segment END
__global__ __launch_bounds__(256) void k_scatter_idx(const int* __restrict__ src, const int* __restrict__ dst,
                                                     const int* __restrict__ et, const int* __restrict__ hist,
                                                     int* __restrict__ offs, int2* __restrict__ ei2, int E) {
  int e = blockIdx.x * 256 + threadIdx.x;
  if (e >= E) return;
  int r = et[e];
  int seg = dst[e] * NR + r;
  int pos = atomicAdd(&offs[seg], 1);
  FU sc;
  sc.f = 1.f / fmaxf((float)hist[seg], 1.f);
  ei2[pos] = make_int2(src[e] * NR + r, sc.i);
}

// ---------- W split+transpose: Wt[c][k], c in [0,1152), k in [0,128) ----------
__global__ __launch_bounds__(128) void k_wsplit(const float* __restrict__ W1, const float* __restrict__ Wr1,
                                                ushort* __restrict__ WtH, ushort* __restrict__ WtL) {
  int c = blockIdx.x;          // 0..1151
  int k = threadIdx.x;         // 0..127
  float v;
  if (c < 1024) {
    int r = c >> 7, col = c & 127;
    v = W1[((size_t)r * 128 + k) * 128 + col];
  } else {
    v = Wr1[(size_t)k * 128 + (c - 1024)];
  }
  ushort hi = f2bf(v);
  ushort lo = f2bf(v - bf2f(hi));
  WtH[(size_t)c * 128 + k] = hi;
  WtL[(size_t)c * 128 + k] = lo;
}

// ---------- dense GEMM: Y[N,1152] = bf16(x[N,128]) @ Wt^T, bf16 out ----------
// Operand swap: D = mfma(A=Wfrag, B=xfrag) -> D[row=Y-col][col=node].
// 256 thr = 4 waves; block = 64 nodes; wave w owns C-panel [w*288, +288).
// 9 chunks = LOOP (unroll 1) of 3 x 3-chunk bodies; W triple-buffered
// (pw0/1/2, 2-kstep lead, period-3 rotation). Barrier-free, no LDS, rule #20.
__global__ __launch_bounds__(256) void k_gemm_dense(
    const float* __restrict__ x,
    const ushort* __restrict__ WtH, const ushort* __restrict__ WtL,
    ushort* __restrict__ Y, int N) {
  int tid = threadIdx.x;
  int w = tid >> 6, lane = tid & 63;
  int n0 = blockIdx.x * 64;
  int wbase = w * 288;

  int frow = lane & 15;
  int fk8 = (lane >> 4) * 8;
  int q4 = (lane >> 4) * 4;

  int anode[4];
  bool nodeok[4];
  size_t ybase[4];
  #pragma unroll
  for (int nf = 0; nf < 4; nf++) {
    int n = n0 + nf * 16 + frow;
    nodeok[nf] = (n < N);
    anode[nf] = nodeok[nf] ? n : (N - 1);
    ybase[nf] = (size_t)anode[nf] * 1152 + q4;
  }

  uint4 xbr[4][4];
  #pragma unroll
  for (int nf = 0; nf < 4; nf++) {
    #pragma unroll
    for (int kc = 0; kc < 4; kc++) {
      const float4* xp = (const float4*)(x + (size_t)anode[nf] * 128 + kc * 32 + fk8);
      float4 v0 = xp[0], v1 = xp[1];
      uint4 o;
      o.x = pk2(v0.x, v0.y);
      o.y = pk2(v0.z, v0.w);
      o.z = pk2(v1.x, v1.y);
      o.w = pk2(v1.z, v1.w);
      xbr[nf][kc] = o;
    }
  }

  f32x4 acc[2][4];
  uint4 pw0[2][2], pw1[2][2], pw2[2][2];  // W frags [cf][plane], triple-buffered

  #define LOADW(P, CB, KC)                                                     \
    {                                                                          \
      _Pragma("unroll")                                                        \
      for (int cf = 0; cf < 2; cf++) {                                         \
        int c_ = (CB) + cf * 16 + frow;                                        \
        P[cf][0] = *(const uint4*)(WtH + (size_t)c_ * 128 + (KC) * 32 + fk8);  \
        P[cf][1] = *(const uint4*)(WtL + (size_t)c_ * 128 + (KC) * 32 + fk8);  \
      }                                                                        \
    }
  #define KSTEP(KC, PWU)                                                       \
    {                                                                          \
      _Pragma("unroll")                                                        \
      for (int cf = 0; cf < 2; cf++) {                                         \
        U128 wh_, wl_;                                                         \
        wh_.u = PWU[cf][0];                                                    \
        wl_.u = PWU[cf][1];                                                    \
        _Pragma("unroll")                                                      \
        for (int nf = 0; nf < 4; nf++) {                                       \
          U128 xv_;                                                            \
          xv_.u = xbr[nf][KC];                                                 \
          acc[cf][nf] = __builtin_amdgcn_mfma_f32_16x16x32_bf16(wh_.s, xv_.s, acc[cf][nf], 0, 0, 0); \
          acc[cf][nf] = __builtin_amdgcn_mfma_f32_16x16x32_bf16(wl_.s, xv_.s, acc[cf][nf], 0, 0, 0); \
        }                                                                      \
      }                                                                        \
    }
  // Entry invariant: X0 = CB.k0, X1 = CB.k1 already loaded (2-kstep lead).
  // DOPF: whether to prefetch NCB's k0/k1 (uniform runtime bool ok).
  #define CHUNK(CB, NCB, X0, X1, X2, DOPF)                                     \
    {                                                                          \
      _Pragma("unroll")                                                        \
      for (int cf = 0; cf < 2; cf++)                                           \
        _Pragma("unroll")                                                      \
        for (int nf = 0; nf < 4; nf++) acc[cf][nf] = (f32x4){0.f, 0.f, 0.f, 0.f}; \
      LOADW(X2, CB, 2);                                                        \
      KSTEP(0, X0);                                                            \
      LOADW(X0, CB, 3);                                                        \
      KSTEP(1, X1);                                                            \
      if (DOPF) { LOADW(X1, NCB, 0); }                                         \
      KSTEP(2, X2);                                                            \
      if (DOPF) { LOADW(X2, NCB, 1); }                                         \
      KSTEP(3, X0);                                                            \
      _Pragma("unroll")                                                        \
      for (int cf = 0; cf < 2; cf++)                                           \
        _Pragma("unroll")                                                      \
        for (int nf = 0; nf < 4; nf++) {                                       \
          if (nodeok[nf]) {                                                    \
            ushort4 o_;                                                        \
            o_.x = f2bf(acc[cf][nf][0]);                                       \
            o_.y = f2bf(acc[cf][nf][1]);                                       \
            o_.z = f2bf(acc[cf][nf][2]);                                       \
            o_.w = f2bf(acc[cf][nf][3]);                                       \
            *(ushort4*)(Y + ybase[nf] + (CB) + cf * 16) = o_;                  \
          }                                                                    \
        }                                                                      \
    }

  LOADW(pw0, wbase, 0);
  LOADW(pw1, wbase, 1);

  int cb = wbase;
  #pragma unroll 1
  for (int c3 = 0; c3 < 3; c3++) {
    bool notlast = (c3 < 2);
    // pw rotation has period 3 -> loop body is rotation-invariant
    CHUNK(cb + 0,  cb + 32, pw0, pw1, pw2, true)
    CHUNK(cb + 32, cb + 64, pw1, pw2, pw0, true)
    CHUNK(cb + 64, cb + 96, pw2, pw0, pw1, notlast)
    cb += 96;
  }

  #undef LOADW
  #undef KSTEP
  #undef CHUNK
}

// ---------- fused h-gather + layer-2 transform: quarter-wave per node ----------
// 256 thr = 16 nodes/block; ql = tid&15 covers cols [ql*8, ql*8+8) (uint4).
// Flat edge loop 8-deep => 32 Y-loads in flight per wave (4 nodes).
__global__ __launch_bounds__(256) void k_hgather(const int* __restrict__ offs, const int* __restrict__ hist,
                                                 const int2* __restrict__ ei2, const ushort* __restrict__ Y,
                                                 const float* __restrict__ b1,
                                                 const float* __restrict__ W2, const float* __restrict__ Wr2,
                                                 float* __restrict__ t, int N) {
  __shared__ float Wt[18 * 128];
  int tid = threadIdx.x;
  for (int i = tid; i < 2304; i += 256) {
    float v; int oc, d;
    if (i < 2048) { int r = i >> 8, rem = i & 255; d = rem >> 1; int c = rem & 1; oc = r * 2 + c; v = W2[i]; }
    else { int i2 = i - 2048; d = i2 >> 1; int c = i2 & 1; oc = 16 + c; v = Wr2[i2]; }
    Wt[oc * 128 + d] = v;
  }
  __syncthreads();

  int node = blockIdx.x * 16 + (tid >> 4);
  int ql = tid & 15;
  if (node >= N) return;
  int c0 = ql * 8;
  int seg0 = node * NR;
  int st = offs[seg0] - hist[seg0];
  int en = offs[seg0 + 7];

  float a[8];
  {
    U128 vr;
    vr.u = *(const uint4*)(Y + (size_t)node * 1152 + 1024 + c0);
    float4 bb0 = *(const float4*)(b1 + c0);
    float4 bb1 = *(const float4*)(b1 + c0 + 4);
    a[0] = bf2f((ushort)vr.s[0]) + bb0.x;
    a[1] = bf2f((ushort)vr.s[1]) + bb0.y;
    a[2] = bf2f((ushort)vr.s[2]) + bb0.z;
    a[3] = bf2f((ushort)vr.s[3]) + bb0.w;
    a[4] = bf2f((ushort)vr.s[4]) + bb1.x;
    a[5] = bf2f((ushort)vr.s[5]) + bb1.y;
    a[6] = bf2f((ushort)vr.s[6]) + bb1.z;
    a[7] = bf2f((ushort)vr.s[7]) + bb1.w;
  }

  #define ACC8(V, SC)                                                          \
    {                                                                          \
      _Pragma("unroll")                                                        \
      for (int j = 0; j < 8; j++) a[j] += bf2f((ushort)(V).s[j]) * (SC);       \
    }

  int i = st;
  for (; i + 8 <= en; i += 8) {
    int2 e0 = ei2[i + 0];
    int2 e1 = ei2[i + 1];
    int2 e2 = ei2[i + 2];
    int2 e3 = ei2[i + 3];
    int2 e4 = ei2[i + 4];
    int2 e5 = ei2[i + 5];
    int2 e6 = ei2[i + 6];
    int2 e7 = ei2[i + 7];
    U128 v0, v1, v2, v3, v4, v5, v6, v7;
    v0.u = *(const uint4*)(Y + (((uint)(e0.x + (e0.x >> 3)) << 7) + c0));
    v1.u = *(const uint4*)(Y + (((uint)(e1.x + (e1.x >> 3)) << 7) + c0));
    v2.u = *(const uint4*)(Y + (((uint)(e2.x + (e2.x >> 3)) << 7) + c0));
    v3.u = *(const uint4*)(Y + (((uint)(e3.x + (e3.x >> 3)) << 7) + c0));
    v4.u = *(const uint4*)(Y + (((uint)(e4.x + (e4.x >> 3)) << 7) + c0));
    v5.u = *(const uint4*)(Y + (((uint)(e5.x + (e5.x >> 3)) << 7) + c0));
    v6.u = *(const uint4*)(Y + (((uint)(e6.x + (e6.x >> 3)) << 7) + c0));
    v7.u = *(const uint4*)(Y + (((uint)(e7.x + (e7.x >> 3)) << 7) + c0));
    FU s0, s1, s2, s3, s4, s5, s6, s7;
    s0.i = e0.y; s1.i = e1.y; s2.i = e2.y; s3.i = e3.y;
    s4.i = e4.y; s5.i = e5.y; s6.i = e6.y; s7.i = e7.y;
    ACC8(v0, s0.f); ACC8(v1, s1.f); ACC8(v2, s2.f); ACC8(v3, s3.f);
    ACC8(v4, s4.f); ACC8(v5, s5.f); ACC8(v6, s6.f); ACC8(v7, s7.f);
  }
  for (; i + 4 <= en; i += 4) {
    int2 e0 = ei2[i + 0];
    int2 e1 = ei2[i + 1];
    int2 e2 = ei2[i + 2];
    int2 e3 = ei2[i + 3];
    U128 v0, v1, v2, v3;
    v0.u = *(const uint4*)(Y + (((uint)(e0.x + (e0.x >> 3)) << 7) + c0));
    v1.u = *(const uint4*)(Y + (((uint)(e1.x + (e1.x >> 3)) << 7) + c0));
    v2.u = *(const uint4*)(Y + (((uint)(e2.x + (e2.x >> 3)) << 7) + c0));
    v3.u = *(const uint4*)(Y + (((uint)(e3.x + (e3.x >> 3)) << 7) + c0));
    FU s0, s1, s2, s3;
    s0.i = e0.y; s1.i = e1.y; s2.i = e2.y; s3.i = e3.y;
    ACC8(v0, s0.f); ACC8(v1, s1.f); ACC8(v2, s2.f); ACC8(v3, s3.f);
  }
  for (; i < en; i++) {
    int2 e = ei2[i];
    U128 v;
    v.u = *(const uint4*)(Y + (((uint)(e.x + (e.x >> 3)) << 7) + c0));
    FU sc; sc.i = e.y;
    ACC8(v, sc.f);
  }
  #undef ACC8

  float h[8];
  #pragma unroll
  for (int j = 0; j < 8; j++) h[j] = fmaxf(a[j], 0.f);

  #pragma unroll
  for (int oc = 0; oc < 18; oc++) {
    float4 wv0 = *(const float4*)(Wt + oc * 128 + c0);
    float4 wv1 = *(const float4*)(Wt + oc * 128 + c0 + 4);
    float p = h[0] * wv0.x + h[1] * wv0.y + h[2] * wv0.z + h[3] * wv0.w +
              h[4] * wv1.x + h[5] * wv1.y + h[6] * wv1.z + h[7] * wv1.w;
    p += __shfl_xor(p, 8);
    p += __shfl_xor(p, 4);
    p += __shfl_xor(p, 2);
    p += __shfl_xor(p, 1);
    if (ql == 0) t[(size_t)node * 18 + oc] = p;
  }
}

// ---------- output: 8 lanes per node (lane = relation), scale pre-folded ----------
__global__ __launch_bounds__(256) void k_out2(const int* __restrict__ offs, const int* __restrict__ hist,
                                              const int2* __restrict__ ei2, const float* __restrict__ t,
                                              const float* __restrict__ b2, float* __restrict__ out, int N) {
  int tid = threadIdx.x;
  int node = blockIdx.x * 32 + (tid >> 3);
  int r = tid & 7;
  if (node >= N) return;
  int seg = node * NR + r;
  int en = offs[seg];
  int cc = hist[seg];
  float s0 = 0.f, s1 = 0.f;
  for (int i = en - cc; i < en; i++) {
    int2 e = ei2[i];
    int src = e.x >> 3;
    FU sc; sc.i = e.y;
    float2 tv = *(const float2*)(t + (size_t)src * 18 + r * 2);
    s0 += tv.x * sc.f;
    s1 += tv.y * sc.f;
  }
  s0 += __shfl_xor(s0, 1); s1 += __shfl_xor(s1, 1);
  s0 += __shfl_xor(s0, 2); s1 += __shfl_xor(s1, 2);
  s0 += __shfl_xor(s0, 4); s1 += __shfl_xor(s1, 4);
  if (r == 0) {
    out[(size_t)node * 2 + 0] = s0 + t[(size_t)node * 18 + 16] + b2[0];
    out[(size_t)node * 2 + 1] = s1 + t[(size_t)node * 18 + 17] + b2[1];
  }
}

extern "C" void kernel_launch(void* const* d_in, const int* in_sizes, int n_in,
                              void* d_out, int out_size, void* d_ws, size_t ws_size,
                              hipStream_t stream) {
  const float* x   = (const float*)d_in[0];
  const int*   ei  = (const int*)d_in[1];
  const int*   et  = (const int*)d_in[2];
  const float* W1  = (const float*)d_in[3];
  const float* Wr1 = (const float*)d_in[4];
  const float* b1  = (const float*)d_in[5];
  const float* W2  = (const float*)d_in[6];
  const float* Wr2 = (const float*)d_in[7];
  const float* b2  = (const float*)d_in[8];
  float* out = (float*)d_out;

  int E = in_sizes[1] / 2;
  int N = in_sizes[0] / DH;
  int S = N * NR;
  const int* src = ei;
  const int* dst = ei + E;

  // ws layout: ints | ei2 (int2, E) | WtH WtL | Y (bf16, N*1152) | t
  int* hist       = (int*)d_ws;                  // S
  int* offs       = hist + S;                    // S
  int* blksum     = offs + S;                    // 1024
  int* blkoff     = blksum + 1024;               // 1024
  int2* ei2       = (int2*)(blkoff + 1024);      // E int2 (8B-aligned)
  size_t int_elems = (size_t)S * 2 + 2048 + (size_t)E * 2;
  int_elems = (int_elems + 3) & ~(size_t)3;      // 16B align
  ushort* WtH = (ushort*)(hist + int_elems);     // 1152*128
  ushort* WtL = WtH + 1152 * 128;                // 1152*128
  ushort* Y   = WtL + 1152 * 128;                // N*1152
  size_t ush_elems = 2 * 1152 * 128 + (size_t)N * 1152;
  ush_elems = (ush_elems + 1) & ~(size_t)1;      // float align
  float* t = (float*)(WtH + ush_elems);          // N*18

  hipMemsetAsync(hist, 0, sizeof(int) * (size_t)S, stream);

  k_hist<<<(E + 255) / 256, 256, 0, stream>>>(dst, et, hist, E);

  int NB = (S + 1023) / 1024;
  k_scan_local<<<NB, 256, 0, stream>>>(hist, offs, blksum, S);
  k_scan_blk<<<1, 512, 0, stream>>>(blksum, blkoff, NB);
  k_scan_add<<<NB, 256, 0, stream>>>(offs, blkoff, S);

  k_scatter_idx<<<(E + 255) / 256, 256, 0, stream>>>(src, dst, et, hist, offs, ei2, E);

  k_wsplit<<<1152, 128, 0, stream>>>(W1, Wr1, WtH, WtL);

  k_gemm_dense<<<(N + 63) / 64, 256, 0, stream>>>(x, WtH, WtL, Y, N);

  k_hgather<<<(N + 15) / 16, 256, 0, stream>>>(offs, hist, ei2, Y, b1, W2, Wr2, t, N);

  k_out2<<<(N + 31) / 32, 256, 0, stream>>>(offs, hist, ei2, t, b2, out, N);
}

// Round 27
// 225.311 us; speedup vs baseline: 1.1104x; 1.1104x over previous
//
#include <hip/hip_runtime.h>
#include <hip/hip_bf16.h>

// RGCN 2-layer forward. Transform-then-aggregate on BOTH layers.
// L1: Y[n,0:1152] = bf16(x[n]) @ [W_r0..W_r7 | Wroot]  (dense bf16 MFMA GEMM,
//     operand-swapped). THIS ROUND: FRAGMENT-MAJOR W layout — wsplit emits
//     WF[cb16][kstep][plane][lane] (the exact uint4 each lane consumes), so
//     every W load is a contiguous 1KB wave transaction (8 sequential lines)
//     instead of 16 scattered 64B lines. Request-count theory for the plateau.
// Sort: counting sort -> ei2[pos] = {src*8+rel, bits(1/cnt)} (mean folded/edge).
// hgather: quarter-wave per node (16 lanes x 8 cols, uint4), 8-deep pipeline;
//     fused layer-2 transform -> t[n,0:18].
// out2: 8 lanes/node (lane=relation), scale pre-folded.

#define NR 8
#define DH 128

typedef short short8 __attribute__((ext_vector_type(8)));
typedef float f32x4 __attribute__((ext_vector_type(4)));

__device__ inline ushort f2bf(float v) {
  __hip_bfloat16 b = __float2bfloat16(v);
  return *reinterpret_cast<ushort*>(&b);
}
__device__ inline float bf2f(ushort u) {
  __hip_bfloat16 b;
  *reinterpret_cast<ushort*>(&b) = u;
  return __bfloat162float(b);
}
__device__ inline uint pk2(float lo, float hi) {
  return (uint)f2bf(lo) | ((uint)f2bf(hi) << 16);
}
union U128 { uint4 u; short8 s; };
union FU { float f; int i; };

// ---------- counting sort ----------
__global__ __launch_bounds__(256) void k_hist(const int* __restrict__ dst, const int* __restrict__ et,
                                              int* __restrict__ hist, int E) {
  int e = blockIdx.x * 256 + threadIdx.x;
  if (e < E) atomicAdd(&hist[dst[e] * NR + et[e]], 1);
}

__global__ __launch_bounds__(256) void k_scan_local(const int* __restrict__ hist, int* __restrict__ offs,
                                                    int* __restrict__ blksum, int S) {
  __shared__ int tsum[256];
  int tid = threadIdx.x;
  int base = blockIdx.x * 1024 + tid * 4;
  int v[4], tot = 0;
  #pragma unroll
  for (int i = 0; i < 4; i++) { v[i] = (base + i < S) ? hist[base + i] : 0; tot += v[i]; }
  tsum[tid] = tot;
  __syncthreads();
  for (int off = 1; off < 256; off <<= 1) {
    int val = tsum[tid];
    int add = (tid >= off) ? tsum[tid - off] : 0;
    __syncthreads();
    tsum[tid] = val + add;
    __syncthreads();
  }
  int run = tsum[tid] - tot;
  #pragma unroll
  for (int i = 0; i < 4; i++) {
    if (base + i < S) offs[base + i] = run;
    run += v[i];
  }
  if (tid == 255) blksum[blockIdx.x] = tsum[255];
}

__global__ __launch_bounds__(512) void k_scan_blk(const int* __restrict__ blksum, int* __restrict__ blkoff, int NB) {
  __shared__ int s[512];
  int tid = threadIdx.x;
  int v = (tid < NB) ? blksum[tid] : 0;
  s[tid] = v;
  __syncthreads();
  for (int off = 1; off < 512; off <<= 1) {
    int val = s[tid];
    int add = (tid >= off) ? s[tid - off] : 0;
    __syncthreads();
    s[tid] = val + add;
    __syncthreads();
  }
  if (tid < NB) blkoff[tid] = s[tid] - v;
}

__global__ __launch_bounds__(256) void k_scan_add(int* __restrict__ offs, const int* __restrict__ blkoff, int S) {
  int tid = threadIdx.x;
  int base = blockIdx.x * 1024 + tid * 4;
  int add = blkoff[blockIdx.x];
  #pragma unroll
  for (int i = 0; i < 4; i++)
    if (base + i < S) offs[base + i] += add;
}

// scatter: ei2[pos] = {src*8+rel, bits(1/cnt)}; offs[seg] becomes segment END
__global__ __launch_bounds__(256) void k_scatter_idx(const int* __restrict__ src, const int* __restrict__ dst,
                                                     const int* __restrict__ et, const int* __restrict__ hist,
                                                     int* __restrict__ offs, int2* __restrict__ ei2, int E) {
  int e = blockIdx.x * 256 + threadIdx.x;
  if (e >= E) return;
  int r = et[e];
  int seg = dst[e] * NR + r;
  int pos = atomicAdd(&offs[seg], 1);
  FU sc;
  sc.f = 1.f / fmaxf((float)hist[seg], 1.f);
  ei2[pos] = make_int2(src[e] * NR + r, sc.i);
}

// ---------- W split+transpose into FRAGMENT-MAJOR layout ----------
// WF[((cb16*4 + KC)*2 + plane)*64 + lane] (uint4 units): the exact fragment
// each lane consumes. cb16 in [0,72) (16 Y-cols each), KC in [0,4), lane: frow=lane&15
// selects the col within the 16-block, g=lane>>4 selects 8 k's.
__global__ __launch_bounds__(256) void k_wsplit(const float* __restrict__ W1, const float* __restrict__ Wr1,
                                                ushort* __restrict__ WF) {
  int cb16 = blockIdx.x;       // 0..71
  int tid = threadIdx.x;
  int KC = tid >> 6;           // 0..3
  int lane = tid & 63;
  int frow = lane & 15, g = lane >> 4;
  int c = cb16 * 16 + frow;    // Y col, 0..1151
  ushort hi[8], lo[8];
  #pragma unroll
  for (int j = 0; j < 8; j++) {
    int k = KC * 32 + g * 8 + j;
    float v;
    if (c < 1024) {
      int r = c >> 7, col = c & 127;
      v = W1[((size_t)r * 128 + k) * 128 + col];
    } else {
      v = Wr1[(size_t)k * 128 + (c - 1024)];
    }
    hi[j] = f2bf(v);
    lo[j] = f2bf(v - bf2f(hi[j]));
  }
  size_t base = ((((size_t)cb16 * 4 + KC) * 2) * 64 + lane) * 8;  // ushort units
  #pragma unroll
  for (int j = 0; j < 8; j++) WF[base + j] = hi[j];
  #pragma unroll
  for (int j = 0; j < 8; j++) WF[base + 512 + j] = lo[j];  // plane stride 64*8
}

// ---------- dense GEMM: Y[N,1152] = bf16(x[N,128]) @ W^T, bf16 out ----------
// Operand swap: D = mfma(A=Wfrag, B=xfrag) -> D[row=Y-col][col=node].
// 256 thr = 4 waves; block = 64 nodes; wave w owns chunks [w*9, w*9+9) (32 cols each).
// W frags loaded CONTIGUOUSLY from fragment-major WF (1KB/wave/load).
// Triple-buffered (pw0/1/2, 2-kstep lead), loop of 3 x 3-chunk bodies.
__global__ __launch_bounds__(256) void k_gemm_dense(
    const float* __restrict__ x, const ushort* __restrict__ WFu,
    ushort* __restrict__ Y, int N) {
  int tid = threadIdx.x;
  int w = tid >> 6, lane = tid & 63;
  int n0 = blockIdx.x * 64;

  int frow = lane & 15;
  int fk8 = (lane >> 4) * 8;
  int q4 = (lane >> 4) * 4;
  const uint4* WF = (const uint4*)WFu;

  int anode[4];
  bool nodeok[4];
  size_t ybase[4];
  #pragma unroll
  for (int nf = 0; nf < 4; nf++) {
    int n = n0 + nf * 16 + frow;
    nodeok[nf] = (n < N);
    anode[nf] = nodeok[nf] ? n : (N - 1);
    ybase[nf] = (size_t)anode[nf] * 1152 + q4;
  }

  uint4 xbr[4][4];
  #pragma unroll
  for (int nf = 0; nf < 4; nf++) {
    #pragma unroll
    for (int kc = 0; kc < 4; kc++) {
      const float4* xp = (const float4*)(x + (size_t)anode[nf] * 128 + kc * 32 + fk8);
      float4 v0 = xp[0], v1 = xp[1];
      uint4 o;
      o.x = pk2(v0.x, v0.y);
      o.y = pk2(v0.z, v0.w);
      o.z = pk2(v1.x, v1.y);
      o.w = pk2(v1.z, v1.w);
      xbr[nf][kc] = o;
    }
  }

  f32x4 acc[2][4];
  uint4 pw0[2][2], pw1[2][2], pw2[2][2];  // W frags [cf][plane], triple-buffered

  // CH = 32-col chunk index (global, 0..35); cb16 = CH*2 + cf.
  #define LOADW(P, CH, KC)                                                     \
    {                                                                          \
      _Pragma("unroll")                                                        \
      for (int cf = 0; cf < 2; cf++) {                                         \
        size_t idx_ = (((size_t)((CH) * 2 + cf) * 4 + (KC)) * 2) * 64 + lane;  \
        P[cf][0] = WF[idx_];                                                   \
        P[cf][1] = WF[idx_ + 64];                                              \
      }                                                                        \
    }
  #define KSTEP(KC, PWU)                                                       \
    {                                                                          \
      _Pragma("unroll")                                                        \
      for (int cf = 0; cf < 2; cf++) {                                         \
        U128 wh_, wl_;                                                         \
        wh_.u = PWU[cf][0];                                                    \
        wl_.u = PWU[cf][1];                                                    \
        _Pragma("unroll")                                                      \
        for (int nf = 0; nf < 4; nf++) {                                       \
          U128 xv_;                                                            \
          xv_.u = xbr[nf][KC];                                                 \
          acc[cf][nf] = __builtin_amdgcn_mfma_f32_16x16x32_bf16(wh_.s, xv_.s, acc[cf][nf], 0, 0, 0); \
          acc[cf][nf] = __builtin_amdgcn_mfma_f32_16x16x32_bf16(wl_.s, xv_.s, acc[cf][nf], 0, 0, 0); \
        }                                                                      \
      }                                                                        \
    }
  // Entry invariant: X0 = CH.k0, X1 = CH.k1 already loaded (2-kstep lead).
  #define CHUNK(CH, NCH, X0, X1, X2, DOPF)                                     \
    {                                                                          \
      _Pragma("unroll")                                                        \
      for (int cf = 0; cf < 2; cf++)                                           \
        _Pragma("unroll")                                                      \
        for (int nf = 0; nf < 4; nf++) acc[cf][nf] = (f32x4){0.f, 0.f, 0.f, 0.f}; \
      LOADW(X2, CH, 2);                                                        \
      KSTEP(0, X0);                                                            \
      LOADW(X0, CH, 3);                                                        \
      KSTEP(1, X1);                                                            \
      if (DOPF) { LOADW(X1, NCH, 0); }                                         \
      KSTEP(2, X2);                                                            \
      if (DOPF) { LOADW(X2, NCH, 1); }                                         \
      KSTEP(3, X0);                                                            \
      _Pragma("unroll")                                                        \
      for (int cf = 0; cf < 2; cf++)                                           \
        _Pragma("unroll")                                                      \
        for (int nf = 0; nf < 4; nf++) {                                       \
          if (nodeok[nf]) {                                                    \
            ushort4 o_;                                                        \
            o_.x = f2bf(acc[cf][nf][0]);                                       \
            o_.y = f2bf(acc[cf][nf][1]);                                       \
            o_.z = f2bf(acc[cf][nf][2]);                                       \
            o_.w = f2bf(acc[cf][nf][3]);                                       \
            *(ushort4*)(Y + ybase[nf] + (CH) * 32 + cf * 16) = o_;             \
          }                                                                    \
        }                                                                      \
    }

  int ch = w * 9;
  LOADW(pw0, ch, 0);
  LOADW(pw1, ch, 1);

  #pragma unroll 1
  for (int c3 = 0; c3 < 3; c3++) {
    bool notlast = (c3 < 2);
    CHUNK(ch + 0, ch + 1, pw0, pw1, pw2, true)
    CHUNK(ch + 1, ch + 2, pw1, pw2, pw0, true)
    CHUNK(ch + 2, ch + 3, pw2, pw0, pw1, notlast)
    ch += 3;
  }

  #undef LOADW
  #undef KSTEP
  #undef CHUNK
}

// ---------- fused h-gather + layer-2 transform: quarter-wave per node ----------
__global__ __launch_bounds__(256) void k_hgather(const int* __restrict__ offs, const int* __restrict__ hist,
                                                 const int2* __restrict__ ei2, const ushort* __restrict__ Y,
                                                 const float* __restrict__ b1,
                                                 const float* __restrict__ W2, const float* __restrict__ Wr2,
                                                 float* __restrict__ t, int N) {
  __shared__ float Wt[18 * 128];
  int tid = threadIdx.x;
  for (int i = tid; i < 2304; i += 256) {
    float v; int oc, d;
    if (i < 2048) { int r = i >> 8, rem = i & 255; d = rem >> 1; int c = rem & 1; oc = r * 2 + c; v = W2[i]; }
    else { int i2 = i - 2048; d = i2 >> 1; int c = i2 & 1; oc = 16 + c; v = Wr2[i2]; }
    Wt[oc * 128 + d] = v;
  }
  __syncthreads();

  int node = blockIdx.x * 16 + (tid >> 4);
  int ql = tid & 15;
  if (node >= N) return;
  int c0 = ql * 8;
  int seg0 = node * NR;
  int st = offs[seg0] - hist[seg0];
  int en = offs[seg0 + 7];

  float a[8];
  {
    U128 vr;
    vr.u = *(const uint4*)(Y + (size_t)node * 1152 + 1024 + c0);
    float4 bb0 = *(const float4*)(b1 + c0);
    float4 bb1 = *(const float4*)(b1 + c0 + 4);
    a[0] = bf2f((ushort)vr.s[0]) + bb0.x;
    a[1] = bf2f((ushort)vr.s[1]) + bb0.y;
    a[2] = bf2f((ushort)vr.s[2]) + bb0.z;
    a[3] = bf2f((ushort)vr.s[3]) + bb0.w;
    a[4] = bf2f((ushort)vr.s[4]) + bb1.x;
    a[5] = bf2f((ushort)vr.s[5]) + bb1.y;
    a[6] = bf2f((ushort)vr.s[6]) + bb1.z;
    a[7] = bf2f((ushort)vr.s[7]) + bb1.w;
  }

  #define ACC8(V, SC)                                                          \
    {                                                                          \
      _Pragma("unroll")                                                        \
      for (int j = 0; j < 8; j++) a[j] += bf2f((ushort)(V).s[j]) * (SC);       \
    }

  int i = st;
  for (; i + 8 <= en; i += 8) {
    int2 e0 = ei2[i + 0];
    int2 e1 = ei2[i + 1];
    int2 e2 = ei2[i + 2];
    int2 e3 = ei2[i + 3];
    int2 e4 = ei2[i + 4];
    int2 e5 = ei2[i + 5];
    int2 e6 = ei2[i + 6];
    int2 e7 = ei2[i + 7];
    U128 v0, v1, v2, v3, v4, v5, v6, v7;
    v0.u = *(const uint4*)(Y + (((uint)(e0.x + (e0.x >> 3)) << 7) + c0));
    v1.u = *(const uint4*)(Y + (((uint)(e1.x + (e1.x >> 3)) << 7) + c0));
    v2.u = *(const uint4*)(Y + (((uint)(e2.x + (e2.x >> 3)) << 7) + c0));
    v3.u = *(const uint4*)(Y + (((uint)(e3.x + (e3.x >> 3)) << 7) + c0));
    v4.u = *(const uint4*)(Y + (((uint)(e4.x + (e4.x >> 3)) << 7) + c0));
    v5.u = *(const uint4*)(Y + (((uint)(e5.x + (e5.x >> 3)) << 7) + c0));
    v6.u = *(const uint4*)(Y + (((uint)(e6.x + (e6.x >> 3)) << 7) + c0));
    v7.u = *(const uint4*)(Y + (((uint)(e7.x + (e7.x >> 3)) << 7) + c0));
    FU s0, s1, s2, s3, s4, s5, s6, s7;
    s0.i = e0.y; s1.i = e1.y; s2.i = e2.y; s3.i = e3.y;
    s4.i = e4.y; s5.i = e5.y; s6.i = e6.y; s7.i = e7.y;
    ACC8(v0, s0.f); ACC8(v1, s1.f); ACC8(v2, s2.f); ACC8(v3, s3.f);
    ACC8(v4, s4.f); ACC8(v5, s5.f); ACC8(v6, s6.f); ACC8(v7, s7.f);
  }
  for (; i + 4 <= en; i += 4) {
    int2 e0 = ei2[i + 0];
    int2 e1 = ei2[i + 1];
    int2 e2 = ei2[i + 2];
    int2 e3 = ei2[i + 3];
    U128 v0, v1, v2, v3;
    v0.u = *(const uint4*)(Y + (((uint)(e0.x + (e0.x >> 3)) << 7) + c0));
    v1.u = *(const uint4*)(Y + (((uint)(e1.x + (e1.x >> 3)) << 7) + c0));
    v2.u = *(const uint4*)(Y + (((uint)(e2.x + (e2.x >> 3)) << 7) + c0));
    v3.u = *(const uint4*)(Y + (((uint)(e3.x + (e3.x >> 3)) << 7) + c0));
    FU s0, s1, s2, s3;
    s0.i = e0.y; s1.i = e1.y; s2.i = e2.y; s3.i = e3.y;
    ACC8(v0, s0.f); ACC8(v1, s1.f); ACC8(v2, s2.f); ACC8(v3, s3.f);
  }
  for (; i < en; i++) {
    int2 e = ei2[i];
    U128 v;
    v.u = *(const uint4*)(Y + (((uint)(e.x + (e.x >> 3)) << 7) + c0));
    FU sc; sc.i = e.y;
    ACC8(v, sc.f);
  }
  #undef ACC8

  float h[8];
  #pragma unroll
  for (int j = 0; j < 8; j++) h[j] = fmaxf(a[j], 0.f);

  #pragma unroll
  for (int oc = 0; oc < 18; oc++) {
    float4 wv0 = *(const float4*)(Wt + oc * 128 + c0);
    float4 wv1 = *(const float4*)(Wt + oc * 128 + c0 + 4);
    float p = h[0] * wv0.x + h[1] * wv0.y + h[2] * wv0.z + h[3] * wv0.w +
              h[4] * wv1.x + h[5] * wv1.y + h[6] * wv1.z + h[7] * wv1.w;
    p += __shfl_xor(p, 8);
    p += __shfl_xor(p, 4);
    p += __shfl_xor(p, 2);
    p += __shfl_xor(p, 1);
    if (ql == 0) t[(size_t)node * 18 + oc] = p;
  }
}

// ---------- output: 8 lanes per node (lane = relation), scale pre-folded ----------
__global__ __launch_bounds__(256) void k_out2(const int* __restrict__ offs, const int* __restrict__ hist,
                                              const int2* __restrict__ ei2, const float* __restrict__ t,
                                              const float* __restrict__ b2, float* __restrict__ out, int N) {
  int tid = threadIdx.x;
  int node = blockIdx.x * 32 + (tid >> 3);
  int r = tid & 7;
  if (node >= N) return;
  int seg = node * NR + r;
  int en = offs[seg];
  int cc = hist[seg];
  float s0 = 0.f, s1 = 0.f;
  for (int i = en - cc; i < en; i++) {
    int2 e = ei2[i];
    int src = e.x >> 3;
    FU sc; sc.i = e.y;
    float2 tv = *(const float2*)(t + (size_t)src * 18 + r * 2);
    s0 += tv.x * sc.f;
    s1 += tv.y * sc.f;
  }
  s0 += __shfl_xor(s0, 1); s1 += __shfl_xor(s1, 1);
  s0 += __shfl_xor(s0, 2); s1 += __shfl_xor(s1, 2);
  s0 += __shfl_xor(s0, 4); s1 += __shfl_xor(s1, 4);
  if (r == 0) {
    out[(size_t)node * 2 + 0] = s0 + t[(size_t)node * 18 + 16] + b2[0];
    out[(size_t)node * 2 + 1] = s1 + t[(size_t)node * 18 + 17] + b2[1];
  }
}

extern "C" void kernel_launch(void* const* d_in, const int* in_sizes, int n_in,
                              void* d_out, int out_size, void* d_ws, size_t ws_size,
                              hipStream_t stream) {
  const float* x   = (const float*)d_in[0];
  const int*   ei  = (const int*)d_in[1];
  const int*   et  = (const int*)d_in[2];
  const float* W1  = (const float*)d_in[3];
  const float* Wr1 = (const float*)d_in[4];
  const float* b1  = (const float*)d_in[5];
  const float* W2  = (const float*)d_in[6];
  const float* Wr2 = (const float*)d_in[7];
  const float* b2  = (const float*)d_in[8];
  float* out = (float*)d_out;

  int E = in_sizes[1] / 2;
  int N = in_sizes[0] / DH;
  int S = N * NR;
  const int* src = ei;
  const int* dst = ei + E;

  // ws layout: ints | ei2 (int2, E) | WF (frag-major, 2*1152*128 ushorts) | Y | t
  int* hist       = (int*)d_ws;                  // S
  int* offs       = hist + S;                    // S
  int* blksum     = offs + S;                    // 1024
  int* blkoff     = blksum + 1024;               // 1024
  int2* ei2       = (int2*)(blkoff + 1024);      // E int2 (8B-aligned)
  size_t int_elems = (size_t)S * 2 + 2048 + (size_t)E * 2;
  int_elems = (int_elems + 3) & ~(size_t)3;      // 16B align
  ushort* WF = (ushort*)(hist + int_elems);      // 72*4*2*64*8 = 294912
  ushort* Y  = WF + 2 * 1152 * 128;              // N*1152
  size_t ush_elems = 2 * 1152 * 128 + (size_t)N * 1152;
  ush_elems = (ush_elems + 1) & ~(size_t)1;      // float align
  float* t = (float*)(WF + ush_elems);           // N*18

  hipMemsetAsync(hist, 0, sizeof(int) * (size_t)S, stream);

  k_hist<<<(E + 255) / 256, 256, 0, stream>>>(dst, et, hist, E);

  int NB = (S + 1023) / 1024;
  k_scan_local<<<NB, 256, 0, stream>>>(hist, offs, blksum, S);
  k_scan_blk<<<1, 512, 0, stream>>>(blksum, blkoff, NB);
  k_scan_add<<<NB, 256, 0, stream>>>(offs, blkoff, S);

  k_scatter_idx<<<(E + 255) / 256, 256, 0, stream>>>(src, dst, et, hist, offs, ei2, E);

  k_wsplit<<<72, 256, 0, stream>>>(W1, Wr1, WF);

  k_gemm_dense<<<(N + 63) / 64, 256, 0, stream>>>(x, WF, Y, N);

  k_hgather<<<(N + 15) / 16, 256, 0, stream>>>(offs, hist, ei2, Y, b1, W2, Wr2, t, N);

  k_out2<<<(N + 31) / 32, 256, 0, stream>>>(offs, hist, ei2, t, b2, out, N);
}

// Round 28
// 202.373 us; speedup vs baseline: 1.2362x; 1.1133x over previous
//
#include <hip/hip_runtime.h>
#include <hip/hip_bf16.h>

// RGCN 2-layer forward. Transform-then-aggregate on BOTH layers.
// L1: Y[n,0:1152] = bf16(x[n]) @ [W_r0..W_r7 | Wroot]  (dense bf16 MFMA GEMM,
//     operand-swapped, fragment-major W (r27: contiguous 1KB W loads)).
//     THIS ROUND: LDS-staged STORE transpose — per (chunk,nf) the 16x32 tile
//     goes through a per-wave LDS buffer and is stored as full 64B lines
//     (lane = node*4+q, uint4 of 8 consecutive cols). Store request-count
//     halves; no partial-line RMW.
// Sort: counting sort -> ei2[pos] = {src*8+rel, bits(1/cnt)} (mean folded/edge).
// hgather: quarter-wave per node (16 lanes x 8 cols, uint4), 8-deep pipeline;
//     fused layer-2 transform -> t[n,0:18].
// out2: 8 lanes/node (lane=relation), scale pre-folded.

#define NR 8
#define DH 128

typedef short short8 __attribute__((ext_vector_type(8)));
typedef float f32x4 __attribute__((ext_vector_type(4)));

__device__ inline ushort f2bf(float v) {
  __hip_bfloat16 b = __float2bfloat16(v);
  return *reinterpret_cast<ushort*>(&b);
}
__device__ inline float bf2f(ushort u) {
  __hip_bfloat16 b;
  *reinterpret_cast<ushort*>(&b) = u;
  return __bfloat162float(b);
}
__device__ inline uint pk2(float lo, float hi) {
  return (uint)f2bf(lo) | ((uint)f2bf(hi) << 16);
}
union U128 { uint4 u; short8 s; };
union FU { float f; int i; };

// ---------- counting sort ----------
__global__ __launch_bounds__(256) void k_hist(const int* __restrict__ dst, const int* __restrict__ et,
                                              int* __restrict__ hist, int E) {
  int e = blockIdx.x * 256 + threadIdx.x;
  if (e < E) atomicAdd(&hist[dst[e] * NR + et[e]], 1);
}

__global__ __launch_bounds__(256) void k_scan_local(const int* __restrict__ hist, int* __restrict__ offs,
                                                    int* __restrict__ blksum, int S) {
  __shared__ int tsum[256];
  int tid = threadIdx.x;
  int base = blockIdx.x * 1024 + tid * 4;
  int v[4], tot = 0;
  #pragma unroll
  for (int i = 0; i < 4; i++) { v[i] = (base + i < S) ? hist[base + i] : 0; tot += v[i]; }
  tsum[tid] = tot;
  __syncthreads();
  for (int off = 1; off < 256; off <<= 1) {
    int val = tsum[tid];
    int add = (tid >= off) ? tsum[tid - off] : 0;
    __syncthreads();
    tsum[tid] = val + add;
    __syncthreads();
  }
  int run = tsum[tid] - tot;
  #pragma unroll
  for (int i = 0; i < 4; i++) {
    if (base + i < S) offs[base + i] = run;
    run += v[i];
  }
  if (tid == 255) blksum[blockIdx.x] = tsum[255];
}

__global__ __launch_bounds__(512) void k_scan_blk(const int* __restrict__ blksum, int* __restrict__ blkoff, int NB) {
  __shared__ int s[512];
  int tid = threadIdx.x;
  int v = (tid < NB) ? blksum[tid] : 0;
  s[tid] = v;
  __syncthreads();
  for (int off = 1; off < 512; off <<= 1) {
    int val = s[tid];
    int add = (tid >= off) ? s[tid - off] : 0;
    __syncthreads();
    s[tid] = val + add;
    __syncthreads();
  }
  if (tid < NB) blkoff[tid] = s[tid] - v;
}

__global__ __launch_bounds__(256) void k_scan_add(int* __restrict__ offs, const int* __restrict__ blkoff, int S) {
  int tid = threadIdx.x;
  int base = blockIdx.x * 1024 + tid * 4;
  int add = blkoff[blockIdx.x];
  #pragma unroll
  for (int i = 0; i < 4; i++)
    if (base + i < S) offs[base + i] += add;
}

// scatter: ei2[pos] = {src*8+rel, bits(1/cnt)}; offs[seg] becomes segment END
__global__ __launch_bounds__(256) void k_scatter_idx(const int* __restrict__ src, const int* __restrict__ dst,
                                                     const int* __restrict__ et, const int* __restrict__ hist,
                                                     int* __restrict__ offs, int2* __restrict__ ei2, int E) {
  int e = blockIdx.x * 256 + threadIdx.x;
  if (e >= E) return;
  int r = et[e];
  int seg = dst[e] * NR + r;
  int pos = atomicAdd(&offs[seg], 1);
  FU sc;
  sc.f = 1.f / fmaxf((float)hist[seg], 1.f);
  ei2[pos] = make_int2(src[e] * NR + r, sc.i);
}

// ---------- W split+transpose into FRAGMENT-MAJOR layout ----------
// WF[((cb16*4 + KC)*2 + plane)*64 + lane] (uint4 units): the exact fragment
// each lane consumes.
__global__ __launch_bounds__(256) void k_wsplit(const float* __restrict__ W1, const float* __restrict__ Wr1,
                                                ushort* __restrict__ WF) {
  int cb16 = blockIdx.x;       // 0..71
  int tid = threadIdx.x;
  int KC = tid >> 6;           // 0..3
  int lane = tid & 63;
  int frow = lane & 15, g = lane >> 4;
  int c = cb16 * 16 + frow;    // Y col, 0..1151
  ushort hi[8], lo[8];
  #pragma unroll
  for (int j = 0; j < 8; j++) {
    int k = KC * 32 + g * 8 + j;
    float v;
    if (c < 1024) {
      int r = c >> 7, col = c & 127;
      v = W1[((size_t)r * 128 + k) * 128 + col];
    } else {
      v = Wr1[(size_t)k * 128 + (c - 1024)];
    }
    hi[j] = f2bf(v);
    lo[j] = f2bf(v - bf2f(hi[j]));
  }
  size_t base = ((((size_t)cb16 * 4 + KC) * 2) * 64 + lane) * 8;  // ushort units
  #pragma unroll
  for (int j = 0; j < 8; j++) WF[base + j] = hi[j];
  #pragma unroll
  for (int j = 0; j < 8; j++) WF[base + 512 + j] = lo[j];  // plane stride 64*8
}

// ---------- dense GEMM: Y[N,1152] = bf16(x[N,128]) @ W^T, bf16 out ----------
// Operand swap; fragment-major W loads (contiguous 1KB/wave); LDS-staged
// full-line stores. 256 thr = 4 waves; block = 64 nodes; wave w owns chunks
// [w*9, w*9+9). Triple-buffered W (2-kstep lead), loop of 3 x 3-chunk bodies.
__global__ __launch_bounds__(256) void k_gemm_dense(
    const float* __restrict__ x, const ushort* __restrict__ WFu,
    ushort* __restrict__ Y, int N) {
  __shared__ ushort stg[4][2][16][40];  // [wave][nf&1][node][40-ushort padded row]
  int tid = threadIdx.x;
  int w = tid >> 6, lane = tid & 63;
  int n0 = blockIdx.x * 64;

  int frow = lane & 15;
  int fk8 = (lane >> 4) * 8;
  int q4 = (lane >> 4) * 4;
  int snd = lane >> 2;        // store: node 0..15
  int sq = lane & 3;          // store: col-quad 0..3 (8 cols each)
  const uint4* WF = (const uint4*)WFu;

  int anode[4];
  #pragma unroll
  for (int nf = 0; nf < 4; nf++) {
    int n = n0 + nf * 16 + frow;
    anode[nf] = (n < N) ? n : (N - 1);  // clamp: OOB rows compute garbage, never stored
  }

  uint4 xbr[4][4];
  #pragma unroll
  for (int nf = 0; nf < 4; nf++) {
    #pragma unroll
    for (int kc = 0; kc < 4; kc++) {
      const float4* xp = (const float4*)(x + (size_t)anode[nf] * 128 + kc * 32 + fk8);
      float4 v0 = xp[0], v1 = xp[1];
      uint4 o;
      o.x = pk2(v0.x, v0.y);
      o.y = pk2(v0.z, v0.w);
      o.z = pk2(v1.x, v1.y);
      o.w = pk2(v1.z, v1.w);
      xbr[nf][kc] = o;
    }
  }

  f32x4 acc[2][4];
  uint4 pw0[2][2], pw1[2][2], pw2[2][2];  // W frags [cf][plane], triple-buffered

  #define LOADW(P, CH, KC)                                                     \
    {                                                                          \
      _Pragma("unroll")                                                        \
      for (int cf = 0; cf < 2; cf++) {                                         \
        size_t idx_ = (((size_t)((CH) * 2 + cf) * 4 + (KC)) * 2) * 64 + lane;  \
        P[cf][0] = WF[idx_];                                                   \
        P[cf][1] = WF[idx_ + 64];                                              \
      }                                                                        \
    }
  #define KSTEP(KC, PWU)                                                       \
    {                                                                          \
      _Pragma("unroll")                                                        \
      for (int cf = 0; cf < 2; cf++) {                                         \
        U128 wh_, wl_;                                                         \
        wh_.u = PWU[cf][0];                                                    \
        wl_.u = PWU[cf][1];                                                    \
        _Pragma("unroll")                                                      \
        for (int nf = 0; nf < 4; nf++) {                                       \
          U128 xv_;                                                            \
          xv_.u = xbr[nf][KC];                                                 \
          acc[cf][nf] = __builtin_amdgcn_mfma_f32_16x16x32_bf16(wh_.s, xv_.s, acc[cf][nf], 0, 0, 0); \
          acc[cf][nf] = __builtin_amdgcn_mfma_f32_16x16x32_bf16(wl_.s, xv_.s, acc[cf][nf], 0, 0, 0); \
        }                                                                      \
      }                                                                        \
    }
  // Store one (chunk,nf) 16x32 tile via per-wave LDS (same-wave handoff),
  // emitting full-64B-line uint4 stores.
  #define STORETILE(CH, NF)                                                    \
    {                                                                          \
      _Pragma("unroll")                                                        \
      for (int cf = 0; cf < 2; cf++) {                                         \
        ushort4 o_;                                                            \
        o_.x = f2bf(acc[cf][NF][0]);                                           \
        o_.y = f2bf(acc[cf][NF][1]);                                           \
        o_.z = f2bf(acc[cf][NF][2]);                                           \
        o_.w = f2bf(acc[cf][NF][3]);                                           \
        *(ushort4*)(&stg[w][(NF) & 1][frow][cf * 16 + q4]) = o_;               \
      }                                                                        \
      uint4 v_ = *(const uint4*)(&stg[w][(NF) & 1][snd][sq * 8]);              \
      int nn_ = n0 + (NF) * 16 + snd;                                          \
      if (nn_ < N)                                                             \
        *(uint4*)(Y + (size_t)nn_ * 1152 + (CH) * 32 + sq * 8) = v_;           \
    }
  // Entry invariant: X0 = CH.k0, X1 = CH.k1 already loaded (2-kstep lead).
  #define CHUNK(CH, NCH, X0, X1, X2, DOPF)                                     \
    {                                                                          \
      _Pragma("unroll")                                                        \
      for (int cf = 0; cf < 2; cf++)                                           \
        _Pragma("unroll")                                                      \
        for (int nf = 0; nf < 4; nf++) acc[cf][nf] = (f32x4){0.f, 0.f, 0.f, 0.f}; \
      LOADW(X2, CH, 2);                                                        \
      KSTEP(0, X0);                                                            \
      LOADW(X0, CH, 3);                                                        \
      KSTEP(1, X1);                                                            \
      if (DOPF) { LOADW(X1, NCH, 0); }                                         \
      KSTEP(2, X2);                                                            \
      if (DOPF) { LOADW(X2, NCH, 1); }                                         \
      KSTEP(3, X0);                                                            \
      STORETILE(CH, 0)                                                         \
      STORETILE(CH, 1)                                                         \
      STORETILE(CH, 2)                                                         \
      STORETILE(CH, 3)                                                         \
    }

  int ch = w * 9;
  LOADW(pw0, ch, 0);
  LOADW(pw1, ch, 1);

  #pragma unroll 1
  for (int c3 = 0; c3 < 3; c3++) {
    bool notlast = (c3 < 2);
    CHUNK(ch + 0, ch + 1, pw0, pw1, pw2, true)
    CHUNK(ch + 1, ch + 2, pw1, pw2, pw0, true)
    CHUNK(ch + 2, ch + 3, pw2, pw0, pw1, notlast)
    ch += 3;
  }

  #undef LOADW
  #undef KSTEP
  #undef STORETILE
  #undef CHUNK
}

// ---------- fused h-gather + layer-2 transform: quarter-wave per node ----------
__global__ __launch_bounds__(256) void k_hgather(const int* __restrict__ offs, const int* __restrict__ hist,
                                                 const int2* __restrict__ ei2, const ushort* __restrict__ Y,
                                                 const float* __restrict__ b1,
                                                 const float* __restrict__ W2, const float* __restrict__ Wr2,
                                                 float* __restrict__ t, int N) {
  __shared__ float Wt[18 * 128];
  int tid = threadIdx.x;
  for (int i = tid; i < 2304; i += 256) {
    float v; int oc, d;
    if (i < 2048) { int r = i >> 8, rem = i & 255; d = rem >> 1; int c = rem & 1; oc = r * 2 + c; v = W2[i]; }
    else { int i2 = i - 2048; d = i2 >> 1; int c = i2 & 1; oc = 16 + c; v = Wr2[i2]; }
    Wt[oc * 128 + d] = v;
  }
  __syncthreads();

  int node = blockIdx.x * 16 + (tid >> 4);
  int ql = tid & 15;
  if (node >= N) return;
  int c0 = ql * 8;
  int seg0 = node * NR;
  int st = offs[seg0] - hist[seg0];
  int en = offs[seg0 + 7];

  float a[8];
  {
    U128 vr;
    vr.u = *(const uint4*)(Y + (size_t)node * 1152 + 1024 + c0);
    float4 bb0 = *(const float4*)(b1 + c0);
    float4 bb1 = *(const float4*)(b1 + c0 + 4);
    a[0] = bf2f((ushort)vr.s[0]) + bb0.x;
    a[1] = bf2f((ushort)vr.s[1]) + bb0.y;
    a[2] = bf2f((ushort)vr.s[2]) + bb0.z;
    a[3] = bf2f((ushort)vr.s[3]) + bb0.w;
    a[4] = bf2f((ushort)vr.s[4]) + bb1.x;
    a[5] = bf2f((ushort)vr.s[5]) + bb1.y;
    a[6] = bf2f((ushort)vr.s[6]) + bb1.z;
    a[7] = bf2f((ushort)vr.s[7]) + bb1.w;
  }

  #define ACC8(V, SC)                                                          \
    {                                                                          \
      _Pragma("unroll")                                                        \
      for (int j = 0; j < 8; j++) a[j] += bf2f((ushort)(V).s[j]) * (SC);       \
    }

  int i = st;
  for (; i + 8 <= en; i += 8) {
    int2 e0 = ei2[i + 0];
    int2 e1 = ei2[i + 1];
    int2 e2 = ei2[i + 2];
    int2 e3 = ei2[i + 3];
    int2 e4 = ei2[i + 4];
    int2 e5 = ei2[i + 5];
    int2 e6 = ei2[i + 6];
    int2 e7 = ei2[i + 7];
    U128 v0, v1, v2, v3, v4, v5, v6, v7;
    v0.u = *(const uint4*)(Y + (((uint)(e0.x + (e0.x >> 3)) << 7) + c0));
    v1.u = *(const uint4*)(Y + (((uint)(e1.x + (e1.x >> 3)) << 7) + c0));
    v2.u = *(const uint4*)(Y + (((uint)(e2.x + (e2.x >> 3)) << 7) + c0));
    v3.u = *(const uint4*)(Y + (((uint)(e3.x + (e3.x >> 3)) << 7) + c0));
    v4.u = *(const uint4*)(Y + (((uint)(e4.x + (e4.x >> 3)) << 7) + c0));
    v5.u = *(const uint4*)(Y + (((uint)(e5.x + (e5.x >> 3)) << 7) + c0));
    v6.u = *(const uint4*)(Y + (((uint)(e6.x + (e6.x >> 3)) << 7) + c0));
    v7.u = *(const uint4*)(Y + (((uint)(e7.x + (e7.x >> 3)) << 7) + c0));
    FU s0, s1, s2, s3, s4, s5, s6, s7;
    s0.i = e0.y; s1.i = e1.y; s2.i = e2.y; s3.i = e3.y;
    s4.i = e4.y; s5.i = e5.y; s6.i = e6.y; s7.i = e7.y;
    ACC8(v0, s0.f); ACC8(v1, s1.f); ACC8(v2, s2.f); ACC8(v3, s3.f);
    ACC8(v4, s4.f); ACC8(v5, s5.f); ACC8(v6, s6.f); ACC8(v7, s7.f);
  }
  for (; i + 4 <= en; i += 4) {
    int2 e0 = ei2[i + 0];
    int2 e1 = ei2[i + 1];
    int2 e2 = ei2[i + 2];
    int2 e3 = ei2[i + 3];
    U128 v0, v1, v2, v3;
    v0.u = *(const uint4*)(Y + (((uint)(e0.x + (e0.x >> 3)) << 7) + c0));
    v1.u = *(const uint4*)(Y + (((uint)(e1.x + (e1.x >> 3)) << 7) + c0));
    v2.u = *(const uint4*)(Y + (((uint)(e2.x + (e2.x >> 3)) << 7) + c0));
    v3.u = *(const uint4*)(Y + (((uint)(e3.x + (e3.x >> 3)) << 7) + c0));
    FU s0, s1, s2, s3;
    s0.i = e0.y; s1.i = e1.y; s2.i = e2.y; s3.i = e3.y;
    ACC8(v0, s0.f); ACC8(v1, s1.f); ACC8(v2, s2.f); ACC8(v3, s3.f);
  }
  for (; i < en; i++) {
    int2 e = ei2[i];
    U128 v;
    v.u = *(const uint4*)(Y + (((uint)(e.x + (e.x >> 3)) << 7) + c0));
    FU sc; sc.i = e.y;
    ACC8(v, sc.f);
  }
  #undef ACC8

  float h[8];
  #pragma unroll
  for (int j = 0; j < 8; j++) h[j] = fmaxf(a[j], 0.f);

  #pragma unroll
  for (int oc = 0; oc < 18; oc++) {
    float4 wv0 = *(const float4*)(Wt + oc * 128 + c0);
    float4 wv1 = *(const float4*)(Wt + oc * 128 + c0 + 4);
    float p = h[0] * wv0.x + h[1] * wv0.y + h[2] * wv0.z + h[3] * wv0.w +
              h[4] * wv1.x + h[5] * wv1.y + h[6] * wv1.z + h[7] * wv1.w;
    p += __shfl_xor(p, 8);
    p += __shfl_xor(p, 4);
    p += __shfl_xor(p, 2);
    p += __shfl_xor(p, 1);
    if (ql == 0) t[(size_t)node * 18 + oc] = p;
  }
}

// ---------- output: 8 lanes per node (lane = relation), scale pre-folded ----------
__global__ __launch_bounds__(256) void k_out2(const int* __restrict__ offs, const int* __restrict__ hist,
                                              const int2* __restrict__ ei2, const float* __restrict__ t,
                                              const float* __restrict__ b2, float* __restrict__ out, int N) {
  int tid = threadIdx.x;
  int node = blockIdx.x * 32 + (tid >> 3);
  int r = tid & 7;
  if (node >= N) return;
  int seg = node * NR + r;
  int en = offs[seg];
  int cc = hist[seg];
  float s0 = 0.f, s1 = 0.f;
  for (int i = en - cc; i < en; i++) {
    int2 e = ei2[i];
    int src = e.x >> 3;
    FU sc; sc.i = e.y;
    float2 tv = *(const float2*)(t + (size_t)src * 18 + r * 2);
    s0 += tv.x * sc.f;
    s1 += tv.y * sc.f;
  }
  s0 += __shfl_xor(s0, 1); s1 += __shfl_xor(s1, 1);
  s0 += __shfl_xor(s0, 2); s1 += __shfl_xor(s1, 2);
  s0 += __shfl_xor(s0, 4); s1 += __shfl_xor(s1, 4);
  if (r == 0) {
    out[(size_t)node * 2 + 0] = s0 + t[(size_t)node * 18 + 16] + b2[0];
    out[(size_t)node * 2 + 1] = s1 + t[(size_t)node * 18 + 17] + b2[1];
  }
}

extern "C" void kernel_launch(void* const* d_in, const int* in_sizes, int n_in,
                              void* d_out, int out_size, void* d_ws, size_t ws_size,
                              hipStream_t stream) {
  const float* x   = (const float*)d_in[0];
  const int*   ei  = (const int*)d_in[1];
  const int*   et  = (const int*)d_in[2];
  const float* W1  = (const float*)d_in[3];
  const float* Wr1 = (const float*)d_in[4];
  const float* b1  = (const float*)d_in[5];
  const float* W2  = (const float*)d_in[6];
  const float* Wr2 = (const float*)d_in[7];
  const float* b2  = (const float*)d_in[8];
  float* out = (float*)d_out;

  int E = in_sizes[1] / 2;
  int N = in_sizes[0] / DH;
  int S = N * NR;
  const int* src = ei;
  const int* dst = ei + E;

  // ws layout: ints | ei2 (int2, E) | WF (frag-major, 2*1152*128 ushorts) | Y | t
  int* hist       = (int*)d_ws;                  // S
  int* offs       = hist + S;                    // S
  int* blksum     = offs + S;                    // 1024
  int* blkoff     = blksum + 1024;               // 1024
  int2* ei2       = (int2*)(blkoff + 1024);      // E int2 (8B-aligned)
  size_t int_elems = (size_t)S * 2 + 2048 + (size_t)E * 2;
  int_elems = (int_elems + 3) & ~(size_t)3;      // 16B align
  ushort* WF = (ushort*)(hist + int_elems);      // 2*1152*128
  ushort* Y  = WF + 2 * 1152 * 128;              // N*1152
  size_t ush_elems = 2 * 1152 * 128 + (size_t)N * 1152;
  ush_elems = (ush_elems + 1) & ~(size_t)1;      // float align
  float* t = (float*)(WF + ush_elems);           // N*18

  hipMemsetAsync(hist, 0, sizeof(int) * (size_t)S, stream);

  k_hist<<<(E + 255) / 256, 256, 0, stream>>>(dst, et, hist, E);

  int NB = (S + 1023) / 1024;
  k_scan_local<<<NB, 256, 0, stream>>>(hist, offs, blksum, S);
  k_scan_blk<<<1, 512, 0, stream>>>(blksum, blkoff, NB);
  k_scan_add<<<NB, 256, 0, stream>>>(offs, blkoff, S);

  k_scatter_idx<<<(E + 255) / 256, 256, 0, stream>>>(src, dst, et, hist, offs, ei2, E);

  k_wsplit<<<72, 256, 0, stream>>>(W1, Wr1, WF);

  k_gemm_dense<<<(N + 63) / 64, 256, 0, stream>>>(x, WF, Y, N);

  k_hgather<<<(N + 15) / 16, 256, 0, stream>>>(offs, hist, ei2, Y, b1, W2, Wr2, t, N);

  k_out2<<<(N + 31) / 32, 256, 0, stream>>>(offs, hist, ei2, t, b2, out, N);
}

// Round 29
// 195.076 us; speedup vs baseline: 1.2824x; 1.0374x over previous
//
#include <hip/hip_runtime.h>
#include <hip/hip_bf16.h>

// RGCN 2-layer forward. Transform-then-aggregate on BOTH layers.
// L1: Y[n,0:1152] = bf16(x[n]) @ [W_r0..W_r7 | Wroot]  (dense bf16 MFMA GEMM,
//     operand-swapped, fragment-major W (r27), LDS-staged full-line stores (r28)).
//     THIS ROUND: cooperative flat-contiguous x staging via LDS (kills the
//     scattered x prologue) + stg rows padded 40->44 ushorts (bank-conflict fix).
// Sort: counting sort -> ei2[pos] = {src*8+rel, bits(1/cnt)} (mean folded/edge).
// hgather: quarter-wave per node (16 lanes x 8 cols, uint4), 8-deep pipeline;
//     fused layer-2 transform -> t[n,0:18].
// out2: 8 lanes/node (lane=relation), scale pre-folded.

#define NR 8
#define DH 128

typedef short short8 __attribute__((ext_vector_type(8)));
typedef float f32x4 __attribute__((ext_vector_type(4)));

__device__ inline ushort f2bf(float v) {
  __hip_bfloat16 b = __float2bfloat16(v);
  return *reinterpret_cast<ushort*>(&b);
}
__device__ inline float bf2f(ushort u) {
  __hip_bfloat16 b;
  *reinterpret_cast<ushort*>(&b) = u;
  return __bfloat162float(b);
}
__device__ inline uint pk2(float lo, float hi) {
  return (uint)f2bf(lo) | ((uint)f2bf(hi) << 16);
}
union U128 { uint4 u; short8 s; };
union FU { float f; int i; };

// ---------- counting sort ----------
__global__ __launch_bounds__(256) void k_hist(const int* __restrict__ dst, const int* __restrict__ et,
                                              int* __restrict__ hist, int E) {
  int e = blockIdx.x * 256 + threadIdx.x;
  if (e < E) atomicAdd(&hist[dst[e] * NR + et[e]], 1);
}

__global__ __launch_bounds__(256) void k_scan_local(const int* __restrict__ hist, int* __restrict__ offs,
                                                    int* __restrict__ blksum, int S) {
  __shared__ int tsum[256];
  int tid = threadIdx.x;
  int base = blockIdx.x * 1024 + tid * 4;
  int v[4], tot = 0;
  #pragma unroll
  for (int i = 0; i < 4; i++) { v[i] = (base + i < S) ? hist[base + i] : 0; tot += v[i]; }
  tsum[tid] = tot;
  __syncthreads();
  for (int off = 1; off < 256; off <<= 1) {
    int val = tsum[tid];
    int add = (tid >= off) ? tsum[tid - off] : 0;
    __syncthreads();
    tsum[tid] = val + add;
    __syncthreads();
  }
  int run = tsum[tid] - tot;
  #pragma unroll
  for (int i = 0; i < 4; i++) {
    if (base + i < S) offs[base + i] = run;
    run += v[i];
  }
  if (tid == 255) blksum[blockIdx.x] = tsum[255];
}

__global__ __launch_bounds__(512) void k_scan_blk(const int* __restrict__ blksum, int* __restrict__ blkoff, int NB) {
  __shared__ int s[512];
  int tid = threadIdx.x;
  int v = (tid < NB) ? blksum[tid] : 0;
  s[tid] = v;
  __syncthreads();
  for (int off = 1; off < 512; off <<= 1) {
    int val = s[tid];
    int add = (tid >= off) ? s[tid - off] : 0;
    __syncthreads();
    s[tid] = val + add;
    __syncthreads();
  }
  if (tid < NB) blkoff[tid] = s[tid] - v;
}

__global__ __launch_bounds__(256) void k_scan_add(int* __restrict__ offs, const int* __restrict__ blkoff, int S) {
  int tid = threadIdx.x;
  int base = blockIdx.x * 1024 + tid * 4;
  int add = blkoff[blockIdx.x];
  #pragma unroll
  for (int i = 0; i < 4; i++)
    if (base + i < S) offs[base + i] += add;
}

// scatter: ei2[pos] = {src*8+rel, bits(1/cnt)}; offs[seg] becomes segment END
__global__ __launch_bounds__(256) void k_scatter_idx(const int* __restrict__ src, const int* __restrict__ dst,
                                                     const int* __restrict__ et, const int* __restrict__ hist,
                                                     int* __restrict__ offs, int2* __restrict__ ei2, int E) {
  int e = blockIdx.x * 256 + threadIdx.x;
  if (e >= E) return;
  int r = et[e];
  int seg = dst[e] * NR + r;
  int pos = atomicAdd(&offs[seg], 1);
  FU sc;
  sc.f = 1.f / fmaxf((float)hist[seg], 1.f);
  ei2[pos] = make_int2(src[e] * NR + r, sc.i);
}

// ---------- W split+transpose into FRAGMENT-MAJOR layout ----------
__global__ __launch_bounds__(256) void k_wsplit(const float* __restrict__ W1, const float* __restrict__ Wr1,
                                                ushort* __restrict__ WF) {
  int cb16 = blockIdx.x;       // 0..71
  int tid = threadIdx.x;
  int KC = tid >> 6;           // 0..3
  int lane = tid & 63;
  int frow = lane & 15, g = lane >> 4;
  int c = cb16 * 16 + frow;    // Y col, 0..1151
  ushort hi[8], lo[8];
  #pragma unroll
  for (int j = 0; j < 8; j++) {
    int k = KC * 32 + g * 8 + j;
    float v;
    if (c < 1024) {
      int r = c >> 7, col = c & 127;
      v = W1[((size_t)r * 128 + k) * 128 + col];
    } else {
      v = Wr1[(size_t)k * 128 + (c - 1024)];
    }
    hi[j] = f2bf(v);
    lo[j] = f2bf(v - bf2f(hi[j]));
  }
  size_t base = ((((size_t)cb16 * 4 + KC) * 2) * 64 + lane) * 8;  // ushort units
  #pragma unroll
  for (int j = 0; j < 8; j++) WF[base + j] = hi[j];
  #pragma unroll
  for (int j = 0; j < 8; j++) WF[base + 512 + j] = lo[j];  // plane stride 64*8
}

// ---------- dense GEMM: Y[N,1152] = bf16(x[N,128]) @ W^T, bf16 out ----------
// Operand swap; fragment-major W loads (contiguous 1KB/wave); LDS-staged x
// (flat-contiguous global reads); LDS-staged full-line stores (44-ushort rows).
// 256 thr = 4 waves; block = 64 nodes; wave w owns chunks [w*9, w*9+9).
// Triple-buffered W (2-kstep lead), loop of 3 x 3-chunk bodies.
__global__ __launch_bounds__(256) void k_gemm_dense(
    const float* __restrict__ x, const ushort* __restrict__ WFu,
    ushort* __restrict__ Y, int N) {
  __shared__ ushort xs[64][136];         // 272B rows: 16B-aligned frag reads
  __shared__ ushort stg[4][2][16][44];   // 88B rows: 16-distinct-bank uint2 reads
  int tid = threadIdx.x;
  int w = tid >> 6, lane = tid & 63;
  int n0 = blockIdx.x * 64;

  int frow = lane & 15;
  int fk8 = (lane >> 4) * 8;
  int snd = lane >> 2;        // store: node 0..15
  int sq = lane & 3;          // store: col-quad 0..3 (8 cols each)
  const uint4* WF = (const uint4*)WFu;

  // cooperative x staging: flat-contiguous reads (1KB/wave/instr), bf16 to LDS
  #pragma unroll
  for (int j = 0; j < 8; j++) {
    int f = j * 1024 + tid * 4;       // flat f32 index in the 64x128 slab
    int nd = f >> 7;
    int cl = f & 127;
    int gn = n0 + nd;
    float4 v = *(const float4*)(x + (size_t)((gn < N) ? gn : (N - 1)) * 128 + cl);
    uint2 o;
    o.x = pk2(v.x, v.y);
    o.y = pk2(v.z, v.w);
    *(uint2*)(&xs[nd][cl]) = o;
  }
  __syncthreads();

  uint4 xbr[4][4];
  #pragma unroll
  for (int nf = 0; nf < 4; nf++)
    #pragma unroll
    for (int kc = 0; kc < 4; kc++)
      xbr[nf][kc] = *(const uint4*)(&xs[nf * 16 + frow][kc * 32 + fk8]);

  f32x4 acc[2][4];
  uint4 pw0[2][2], pw1[2][2], pw2[2][2];  // W frags [cf][plane], triple-buffered

  #define LOADW(P, CH, KC)                                                     \
    {                                                                          \
      _Pragma("unroll")                                                        \
      for (int cf = 0; cf < 2; cf++) {                                         \
        size_t idx_ = (((size_t)((CH) * 2 + cf) * 4 + (KC)) * 2) * 64 + lane;  \
        P[cf][0] = WF[idx_];                                                   \
        P[cf][1] = WF[idx_ + 64];                                              \
      }                                                                        \
    }
  #define KSTEP(KC, PWU)                                                       \
    {                                                                          \
      _Pragma("unroll")                                                        \
      for (int cf = 0; cf < 2; cf++) {                                         \
        U128 wh_, wl_;                                                         \
        wh_.u = PWU[cf][0];                                                    \
        wl_.u = PWU[cf][1];                                                    \
        _Pragma("unroll")                                                      \
        for (int nf = 0; nf < 4; nf++) {                                       \
          U128 xv_;                                                            \
          xv_.u = xbr[nf][KC];                                                 \
          acc[cf][nf] = __builtin_amdgcn_mfma_f32_16x16x32_bf16(wh_.s, xv_.s, acc[cf][nf], 0, 0, 0); \
          acc[cf][nf] = __builtin_amdgcn_mfma_f32_16x16x32_bf16(wl_.s, xv_.s, acc[cf][nf], 0, 0, 0); \
        }                                                                      \
      }                                                                        \
    }
  // Store one (chunk,nf) 16x32 tile via per-wave LDS (same-wave handoff),
  // emitting full-64B-line uint4 stores.
  #define STORETILE(CH, NF)                                                    \
    {                                                                          \
      _Pragma("unroll")                                                        \
      for (int cf = 0; cf < 2; cf++) {                                         \
        ushort4 o_;                                                            \
        o_.x = f2bf(acc[cf][NF][0]);                                           \
        o_.y = f2bf(acc[cf][NF][1]);                                           \
        o_.z = f2bf(acc[cf][NF][2]);                                           \
        o_.w = f2bf(acc[cf][NF][3]);                                           \
        *(ushort4*)(&stg[w][(NF) & 1][frow][cf * 16 + (fk8 >> 1)]) = o_;       \
      }                                                                        \
      uint2 va_ = *(const uint2*)(&stg[w][(NF) & 1][snd][sq * 8]);             \
      uint2 vb_ = *(const uint2*)(&stg[w][(NF) & 1][snd][sq * 8 + 4]);         \
      int nn_ = n0 + (NF) * 16 + snd;                                          \
      if (nn_ < N) {                                                           \
        uint4 v_ = make_uint4(va_.x, va_.y, vb_.x, vb_.y);                     \
        *(uint4*)(Y + (size_t)nn_ * 1152 + (CH) * 32 + sq * 8) = v_;           \
      }                                                                        \
    }
  // Entry invariant: X0 = CH.k0, X1 = CH.k1 already loaded (2-kstep lead).
  #define CHUNK(CH, NCH, X0, X1, X2, DOPF)                                     \
    {                                                                          \
      _Pragma("unroll")                                                        \
      for (int cf = 0; cf < 2; cf++)                                           \
        _Pragma("unroll")                                                      \
        for (int nf = 0; nf < 4; nf++) acc[cf][nf] = (f32x4){0.f, 0.f, 0.f, 0.f}; \
      LOADW(X2, CH, 2);                                                        \
      KSTEP(0, X0);                                                            \
      LOADW(X0, CH, 3);                                                        \
      KSTEP(1, X1);                                                            \
      if (DOPF) { LOADW(X1, NCH, 0); }                                         \
      KSTEP(2, X2);                                                            \
      if (DOPF) { LOADW(X2, NCH, 1); }                                         \
      KSTEP(3, X0);                                                            \
      STORETILE(CH, 0)                                                         \
      STORETILE(CH, 1)                                                         \
      STORETILE(CH, 2)                                                         \
      STORETILE(CH, 3)                                                         \
    }

  int ch = w * 9;
  LOADW(pw0, ch, 0);
  LOADW(pw1, ch, 1);

  #pragma unroll 1
  for (int c3 = 0; c3 < 3; c3++) {
    bool notlast = (c3 < 2);
    CHUNK(ch + 0, ch + 1, pw0, pw1, pw2, true)
    CHUNK(ch + 1, ch + 2, pw1, pw2, pw0, true)
    CHUNK(ch + 2, ch + 3, pw2, pw0, pw1, notlast)
    ch += 3;
  }

  #undef LOADW
  #undef KSTEP
  #undef STORETILE
  #undef CHUNK
}

// ---------- fused h-gather + layer-2 transform: quarter-wave per node ----------
__global__ __launch_bounds__(256) void k_hgather(const int* __restrict__ offs, const int* __restrict__ hist,
                                                 const int2* __restrict__ ei2, const ushort* __restrict__ Y,
                                                 const float* __restrict__ b1,
                                                 const float* __restrict__ W2, const float* __restrict__ Wr2,
                                                 float* __restrict__ t, int N) {
  __shared__ float Wt[18 * 128];
  int tid = threadIdx.x;
  for (int i = tid; i < 2304; i += 256) {
    float v; int oc, d;
    if (i < 2048) { int r = i >> 8, rem = i & 255; d = rem >> 1; int c = rem & 1; oc = r * 2 + c; v = W2[i]; }
    else { int i2 = i - 2048; d = i2 >> 1; int c = i2 & 1; oc = 16 + c; v = Wr2[i2]; }
    Wt[oc * 128 + d] = v;
  }
  __syncthreads();

  int node = blockIdx.x * 16 + (tid >> 4);
  int ql = tid & 15;
  if (node >= N) return;
  int c0 = ql * 8;
  int seg0 = node * NR;
  int st = offs[seg0] - hist[seg0];
  int en = offs[seg0 + 7];

  float a[8];
  {
    U128 vr;
    vr.u = *(const uint4*)(Y + (size_t)node * 1152 + 1024 + c0);
    float4 bb0 = *(const float4*)(b1 + c0);
    float4 bb1 = *(const float4*)(b1 + c0 + 4);
    a[0] = bf2f((ushort)vr.s[0]) + bb0.x;
    a[1] = bf2f((ushort)vr.s[1]) + bb0.y;
    a[2] = bf2f((ushort)vr.s[2]) + bb0.z;
    a[3] = bf2f((ushort)vr.s[3]) + bb0.w;
    a[4] = bf2f((ushort)vr.s[4]) + bb1.x;
    a[5] = bf2f((ushort)vr.s[5]) + bb1.y;
    a[6] = bf2f((ushort)vr.s[6]) + bb1.z;
    a[7] = bf2f((ushort)vr.s[7]) + bb1.w;
  }

  #define ACC8(V, SC)                                                          \
    {                                                                          \
      _Pragma("unroll")                                                        \
      for (int j = 0; j < 8; j++) a[j] += bf2f((ushort)(V).s[j]) * (SC);       \
    }

  int i = st;
  for (; i + 8 <= en; i += 8) {
    int2 e0 = ei2[i + 0];
    int2 e1 = ei2[i + 1];
    int2 e2 = ei2[i + 2];
    int2 e3 = ei2[i + 3];
    int2 e4 = ei2[i + 4];
    int2 e5 = ei2[i + 5];
    int2 e6 = ei2[i + 6];
    int2 e7 = ei2[i + 7];
    U128 v0, v1, v2, v3, v4, v5, v6, v7;
    v0.u = *(const uint4*)(Y + (((uint)(e0.x + (e0.x >> 3)) << 7) + c0));
    v1.u = *(const uint4*)(Y + (((uint)(e1.x + (e1.x >> 3)) << 7) + c0));
    v2.u = *(const uint4*)(Y + (((uint)(e2.x + (e2.x >> 3)) << 7) + c0));
    v3.u = *(const uint4*)(Y + (((uint)(e3.x + (e3.x >> 3)) << 7) + c0));
    v4.u = *(const uint4*)(Y + (((uint)(e4.x + (e4.x >> 3)) << 7) + c0));
    v5.u = *(const uint4*)(Y + (((uint)(e5.x + (e5.x >> 3)) << 7) + c0));
    v6.u = *(const uint4*)(Y + (((uint)(e6.x + (e6.x >> 3)) << 7) + c0));
    v7.u = *(const uint4*)(Y + (((uint)(e7.x + (e7.x >> 3)) << 7) + c0));
    FU s0, s1, s2, s3, s4, s5, s6, s7;
    s0.i = e0.y; s1.i = e1.y; s2.i = e2.y; s3.i = e3.y;
    s4.i = e4.y; s5.i = e5.y; s6.i = e6.y; s7.i = e7.y;
    ACC8(v0, s0.f); ACC8(v1, s1.f); ACC8(v2, s2.f); ACC8(v3, s3.f);
    ACC8(v4, s4.f); ACC8(v5, s5.f); ACC8(v6, s6.f); ACC8(v7, s7.f);
  }
  for (; i + 4 <= en; i += 4) {
    int2 e0 = ei2[i + 0];
    int2 e1 = ei2[i + 1];
    int2 e2 = ei2[i + 2];
    int2 e3 = ei2[i + 3];
    U128 v0, v1, v2, v3;
    v0.u = *(const uint4*)(Y + (((uint)(e0.x + (e0.x >> 3)) << 7) + c0));
    v1.u = *(const uint4*)(Y + (((uint)(e1.x + (e1.x >> 3)) << 7) + c0));
    v2.u = *(const uint4*)(Y + (((uint)(e2.x + (e2.x >> 3)) << 7) + c0));
    v3.u = *(const uint4*)(Y + (((uint)(e3.x + (e3.x >> 3)) << 7) + c0));
    FU s0, s1, s2, s3;
    s0.i = e0.y; s1.i = e1.y; s2.i = e2.y; s3.i = e3.y;
    ACC8(v0, s0.f); ACC8(v1, s1.f); ACC8(v2, s2.f); ACC8(v3, s3.f);
  }
  for (; i < en; i++) {
    int2 e = ei2[i];
    U128 v;
    v.u = *(const uint4*)(Y + (((uint)(e.x + (e.x >> 3)) << 7) + c0));
    FU sc; sc.i = e.y;
    ACC8(v, sc.f);
  }
  #undef ACC8

  float h[8];
  #pragma unroll
  for (int j = 0; j < 8; j++) h[j] = fmaxf(a[j], 0.f);

  #pragma unroll
  for (int oc = 0; oc < 18; oc++) {
    float4 wv0 = *(const float4*)(Wt + oc * 128 + c0);
    float4 wv1 = *(const float4*)(Wt + oc * 128 + c0 + 4);
    float p = h[0] * wv0.x + h[1] * wv0.y + h[2] * wv0.z + h[3] * wv0.w +
              h[4] * wv1.x + h[5] * wv1.y + h[6] * wv1.z + h[7] * wv1.w;
    p += __shfl_xor(p, 8);
    p += __shfl_xor(p, 4);
    p += __shfl_xor(p, 2);
    p += __shfl_xor(p, 1);
    if (ql == 0) t[(size_t)node * 18 + oc] = p;
  }
}

// ---------- output: 8 lanes per node (lane = relation), scale pre-folded ----------
__global__ __launch_bounds__(256) void k_out2(const int* __restrict__ offs, const int* __restrict__ hist,
                                              const int2* __restrict__ ei2, const float* __restrict__ t,
                                              const float* __restrict__ b2, float* __restrict__ out, int N) {
  int tid = threadIdx.x;
  int node = blockIdx.x * 32 + (tid >> 3);
  int r = tid & 7;
  if (node >= N) return;
  int seg = node * NR + r;
  int en = offs[seg];
  int cc = hist[seg];
  float s0 = 0.f, s1 = 0.f;
  for (int i = en - cc; i < en; i++) {
    int2 e = ei2[i];
    int src = e.x >> 3;
    FU sc; sc.i = e.y;
    float2 tv = *(const float2*)(t + (size_t)src * 18 + r * 2);
    s0 += tv.x * sc.f;
    s1 += tv.y * sc.f;
  }
  s0 += __shfl_xor(s0, 1); s1 += __shfl_xor(s1, 1);
  s0 += __shfl_xor(s0, 2); s1 += __shfl_xor(s1, 2);
  s0 += __shfl_xor(s0, 4); s1 += __shfl_xor(s1, 4);
  if (r == 0) {
    out[(size_t)node * 2 + 0] = s0 + t[(size_t)node * 18 + 16] + b2[0];
    out[(size_t)node * 2 + 1] = s1 + t[(size_t)node * 18 + 17] + b2[1];
  }
}

extern "C" void kernel_launch(void* const* d_in, const int* in_sizes, int n_in,
                              void* d_out, int out_size, void* d_ws, size_t ws_size,
                              hipStream_t stream) {
  const float* x   = (const float*)d_in[0];
  const int*   ei  = (const int*)d_in[1];
  const int*   et  = (const int*)d_in[2];
  const float* W1  = (const float*)d_in[3];
  const float* Wr1 = (const float*)d_in[4];
  const float* b1  = (const float*)d_in[5];
  const float* W2  = (const float*)d_in[6];
  const float* Wr2 = (const float*)d_in[7];
  const float* b2  = (const float*)d_in[8];
  float* out = (float*)d_out;

  int E = in_sizes[1] / 2;
  int N = in_sizes[0] / DH;
  int S = N * NR;
  const int* src = ei;
  const int* dst = ei + E;

  // ws layout: ints | ei2 (int2, E) | WF (frag-major, 2*1152*128 ushorts) | Y | t
  int* hist       = (int*)d_ws;                  // S
  int* offs       = hist + S;                    // S
  int* blksum     = offs + S;                    // 1024
  int* blkoff     = blksum + 1024;               // 1024
  int2* ei2       = (int2*)(blkoff + 1024);      // E int2 (8B-aligned)
  size_t int_elems = (size_t)S * 2 + 2048 + (size_t)E * 2;
  int_elems = (int_elems + 3) & ~(size_t)3;      // 16B align
  ushort* WF = (ushort*)(hist + int_elems);      // 2*1152*128
  ushort* Y  = WF + 2 * 1152 * 128;              // N*1152
  size_t ush_elems = 2 * 1152 * 128 + (size_t)N * 1152;
  ush_elems = (ush_elems + 1) & ~(size_t)1;      // float align
  float* t = (float*)(WF + ush_elems);           // N*18

  hipMemsetAsync(hist, 0, sizeof(int) * (size_t)S, stream);

  k_hist<<<(E + 255) / 256, 256, 0, stream>>>(dst, et, hist, E);

  int NB = (S + 1023) / 1024;
  k_scan_local<<<NB, 256, 0, stream>>>(hist, offs, blksum, S);
  k_scan_blk<<<1, 512, 0, stream>>>(blksum, blkoff, NB);
  k_scan_add<<<NB, 256, 0, stream>>>(offs, blkoff, S);

  k_scatter_idx<<<(E + 255) / 256, 256, 0, stream>>>(src, dst, et, hist, offs, ei2, E);

  k_wsplit<<<72, 256, 0, stream>>>(W1, Wr1, WF);

  k_gemm_dense<<<(N + 63) / 64, 256, 0, stream>>>(x, WF, Y, N);

  k_hgather<<<(N + 15) / 16, 256, 0, stream>>>(offs, hist, ei2, Y, b1, W2, Wr2, t, N);

  k_out2<<<(N + 31) / 32, 256, 0, stream>>>(offs, hist, ei2, t, b2, out, N);
}

// Round 30
// 190.113 us; speedup vs baseline: 1.3159x; 1.0261x over previous
//
#include <hip/hip_runtime.h>
#include <hip/hip_bf16.h>

// RGCN 2-layer forward. Transform-then-aggregate on BOTH layers.
// L1: Y[n,0:1152] = bf16(x[n]) @ [W_r0..W_r7 | Wroot]  (dense bf16 MFMA GEMM,
//     operand-swapped, fragment-major W (r27), LDS-staged x + full-line stores
//     (r28/r29)).
// Sort: counting sort -> ei2[pos] = {src*8+rel, bits(1/cnt)} (mean folded/edge).
//     THIS ROUND: scan_add pass eliminated — blkoff folded into consumers
//     (all 8 segments of a node share one 1024-scan-block since 8 | 1024).
// hgather: quarter-wave per node (16 lanes x 8 cols, uint4), 8-deep pipeline;
//     fused layer-2 transform -> t[n,0:18].
// out2: 8 lanes/node (lane=relation), scale pre-folded.

#define NR 8
#define DH 128

typedef short short8 __attribute__((ext_vector_type(8)));
typedef float f32x4 __attribute__((ext_vector_type(4)));

__device__ inline ushort f2bf(float v) {
  __hip_bfloat16 b = __float2bfloat16(v);
  return *reinterpret_cast<ushort*>(&b);
}
__device__ inline float bf2f(ushort u) {
  __hip_bfloat16 b;
  *reinterpret_cast<ushort*>(&b) = u;
  return __bfloat162float(b);
}
__device__ inline uint pk2(float lo, float hi) {
  return (uint)f2bf(lo) | ((uint)f2bf(hi) << 16);
}
union U128 { uint4 u; short8 s; };
union FU { float f; int i; };

// ---------- counting sort ----------
__global__ __launch_bounds__(256) void k_hist(const int* __restrict__ dst, const int* __restrict__ et,
                                              int* __restrict__ hist, int E) {
  int e = blockIdx.x * 256 + threadIdx.x;
  if (e < E) atomicAdd(&hist[dst[e] * NR + et[e]], 1);
}

__global__ __launch_bounds__(256) void k_scan_local(const int* __restrict__ hist, int* __restrict__ offs,
                                                    int* __restrict__ blksum, int S) {
  __shared__ int tsum[256];
  int tid = threadIdx.x;
  int base = blockIdx.x * 1024 + tid * 4;
  int v[4], tot = 0;
  #pragma unroll
  for (int i = 0; i < 4; i++) { v[i] = (base + i < S) ? hist[base + i] : 0; tot += v[i]; }
  tsum[tid] = tot;
  __syncthreads();
  for (int off = 1; off < 256; off <<= 1) {
    int val = tsum[tid];
    int add = (tid >= off) ? tsum[tid - off] : 0;
    __syncthreads();
    tsum[tid] = val + add;
    __syncthreads();
  }
  int run = tsum[tid] - tot;
  #pragma unroll
  for (int i = 0; i < 4; i++) {
    if (base + i < S) offs[base + i] = run;
    run += v[i];
  }
  if (tid == 255) blksum[blockIdx.x] = tsum[255];
}

__global__ __launch_bounds__(512) void k_scan_blk(const int* __restrict__ blksum, int* __restrict__ blkoff, int NB) {
  __shared__ int s[512];
  int tid = threadIdx.x;
  int v = (tid < NB) ? blksum[tid] : 0;
  s[tid] = v;
  __syncthreads();
  for (int off = 1; off < 512; off <<= 1) {
    int val = s[tid];
    int add = (tid >= off) ? s[tid - off] : 0;
    __syncthreads();
    s[tid] = val + add;
    __syncthreads();
  }
  if (tid < NB) blkoff[tid] = s[tid] - v;
}

// scatter: ei2[pos] = {src*8+rel, bits(1/cnt)}; offs stays LOCAL (blkoff folded
// in here and in consumers); offs[seg] becomes local segment END.
__global__ __launch_bounds__(256) void k_scatter_idx(const int* __restrict__ src, const int* __restrict__ dst,
                                                     const int* __restrict__ et, const int* __restrict__ hist,
                                                     const int* __restrict__ blkoff,
                                                     int* __restrict__ offs, int2* __restrict__ ei2, int E) {
  int e = blockIdx.x * 256 + threadIdx.x;
  if (e >= E) return;
  int r = et[e];
  int seg = dst[e] * NR + r;
  int pos = atomicAdd(&offs[seg], 1) + blkoff[seg >> 10];
  FU sc;
  sc.f = 1.f / fmaxf((float)hist[seg], 1.f);
  ei2[pos] = make_int2(src[e] * NR + r, sc.i);
}

// ---------- W split+transpose into FRAGMENT-MAJOR layout ----------
__global__ __launch_bounds__(256) void k_wsplit(const float* __restrict__ W1, const float* __restrict__ Wr1,
                                                ushort* __restrict__ WF) {
  int cb16 = blockIdx.x;       // 0..71
  int tid = threadIdx.x;
  int KC = tid >> 6;           // 0..3
  int lane = tid & 63;
  int frow = lane & 15, g = lane >> 4;
  int c = cb16 * 16 + frow;    // Y col, 0..1151
  ushort hi[8], lo[8];
  #pragma unroll
  for (int j = 0; j < 8; j++) {
    int k = KC * 32 + g * 8 + j;
    float v;
    if (c < 1024) {
      int r = c >> 7, col = c & 127;
      v = W1[((size_t)r * 128 + k) * 128 + col];
    } else {
      v = Wr1[(size_t)k * 128 + (c - 1024)];
    }
    hi[j] = f2bf(v);
    lo[j] = f2bf(v - bf2f(hi[j]));
  }
  size_t base = ((((size_t)cb16 * 4 + KC) * 2) * 64 + lane) * 8;  // ushort units
  #pragma unroll
  for (int j = 0; j < 8; j++) WF[base + j] = hi[j];
  #pragma unroll
  for (int j = 0; j < 8; j++) WF[base + 512 + j] = lo[j];  // plane stride 64*8
}

// ---------- dense GEMM: Y[N,1152] = bf16(x[N,128]) @ W^T, bf16 out ----------
__global__ __launch_bounds__(256) void k_gemm_dense(
    const float* __restrict__ x, const ushort* __restrict__ WFu,
    ushort* __restrict__ Y, int N) {
  __shared__ ushort xs[64][136];         // 272B rows: 16B-aligned frag reads
  __shared__ ushort stg[4][2][16][44];   // 88B rows: 16-distinct-bank uint2 reads
  int tid = threadIdx.x;
  int w = tid >> 6, lane = tid & 63;
  int n0 = blockIdx.x * 64;

  int frow = lane & 15;
  int fk8 = (lane >> 4) * 8;
  int snd = lane >> 2;        // store: node 0..15
  int sq = lane & 3;          // store: col-quad 0..3 (8 cols each)
  const uint4* WF = (const uint4*)WFu;

  // cooperative x staging: flat-contiguous reads (1KB/wave/instr), bf16 to LDS
  #pragma unroll
  for (int j = 0; j < 8; j++) {
    int f = j * 1024 + tid * 4;       // flat f32 index in the 64x128 slab
    int nd = f >> 7;
    int cl = f & 127;
    int gn = n0 + nd;
    float4 v = *(const float4*)(x + (size_t)((gn < N) ? gn : (N - 1)) * 128 + cl);
    uint2 o;
    o.x = pk2(v.x, v.y);
    o.y = pk2(v.z, v.w);
    *(uint2*)(&xs[nd][cl]) = o;
  }
  __syncthreads();

  uint4 xbr[4][4];
  #pragma unroll
  for (int nf = 0; nf < 4; nf++)
    #pragma unroll
    for (int kc = 0; kc < 4; kc++)
      xbr[nf][kc] = *(const uint4*)(&xs[nf * 16 + frow][kc * 32 + fk8]);

  f32x4 acc[2][4];
  uint4 pw0[2][2], pw1[2][2], pw2[2][2];  // W frags [cf][plane], triple-buffered

  #define LOADW(P, CH, KC)                                                     \
    {                                                                          \
      _Pragma("unroll")                                                        \
      for (int cf = 0; cf < 2; cf++) {                                         \
        size_t idx_ = (((size_t)((CH) * 2 + cf) * 4 + (KC)) * 2) * 64 + lane;  \
        P[cf][0] = WF[idx_];                                                   \
        P[cf][1] = WF[idx_ + 64];                                              \
      }                                                                        \
    }
  #define KSTEP(KC, PWU)                                                       \
    {                                                                          \
      _Pragma("unroll")                                                        \
      for (int cf = 0; cf < 2; cf++) {                                         \
        U128 wh_, wl_;                                                         \
        wh_.u = PWU[cf][0];                                                    \
        wl_.u = PWU[cf][1];                                                    \
        _Pragma("unroll")                                                      \
        for (int nf = 0; nf < 4; nf++) {                                       \
          U128 xv_;                                                            \
          xv_.u = xbr[nf][KC];                                                 \
          acc[cf][nf] = __builtin_amdgcn_mfma_f32_16x16x32_bf16(wh_.s, xv_.s, acc[cf][nf], 0, 0, 0); \
          acc[cf][nf] = __builtin_amdgcn_mfma_f32_16x16x32_bf16(wl_.s, xv_.s, acc[cf][nf], 0, 0, 0); \
        }                                                                      \
      }                                                                        \
    }
  #define STORETILE(CH, NF)                                                    \
    {                                                                          \
      _Pragma("unroll")                                                        \
      for (int cf = 0; cf < 2; cf++) {                                         \
        ushort4 o_;                                                            \
        o_.x = f2bf(acc[cf][NF][0]);                                           \
        o_.y = f2bf(acc[cf][NF][1]);                                           \
        o_.z = f2bf(acc[cf][NF][2]);                                           \
        o_.w = f2bf(acc[cf][NF][3]);                                           \
        *(ushort4*)(&stg[w][(NF) & 1][frow][cf * 16 + (fk8 >> 1)]) = o_;       \
      }                                                                        \
      uint2 va_ = *(const uint2*)(&stg[w][(NF) & 1][snd][sq * 8]);             \
      uint2 vb_ = *(const uint2*)(&stg[w][(NF) & 1][snd][sq * 8 + 4]);         \
      int nn_ = n0 + (NF) * 16 + snd;                                          \
      if (nn_ < N) {                                                           \
        uint4 v_ = make_uint4(va_.x, va_.y, vb_.x, vb_.y);                     \
        *(uint4*)(Y + (size_t)nn_ * 1152 + (CH) * 32 + sq * 8) = v_;           \
      }                                                                        \
    }
  #define CHUNK(CH, NCH, X0, X1, X2, DOPF)                                     \
    {                                                                          \
      _Pragma("unroll")                                                        \
      for (int cf = 0; cf < 2; cf++)                                           \
        _Pragma("unroll")                                                      \
        for (int nf = 0; nf < 4; nf++) acc[cf][nf] = (f32x4){0.f, 0.f, 0.f, 0.f}; \
      LOADW(X2, CH, 2);                                                        \
      KSTEP(0, X0);                                                            \
      LOADW(X0, CH, 3);                                                        \
      KSTEP(1, X1);                                                            \
      if (DOPF) { LOADW(X1, NCH, 0); }                                         \
      KSTEP(2, X2);                                                            \
      if (DOPF) { LOADW(X2, NCH, 1); }                                         \
      KSTEP(3, X0);                                                            \
      STORETILE(CH, 0)                                                         \
      STORETILE(CH, 1)                                                         \
      STORETILE(CH, 2)                                                         \
      STORETILE(CH, 3)                                                         \
    }

  int ch = w * 9;
  LOADW(pw0, ch, 0);
  LOADW(pw1, ch, 1);

  #pragma unroll 1
  for (int c3 = 0; c3 < 3; c3++) {
    bool notlast = (c3 < 2);
    CHUNK(ch + 0, ch + 1, pw0, pw1, pw2, true)
    CHUNK(ch + 1, ch + 2, pw1, pw2, pw0, true)
    CHUNK(ch + 2, ch + 3, pw2, pw0, pw1, notlast)
    ch += 3;
  }

  #undef LOADW
  #undef KSTEP
  #undef STORETILE
  #undef CHUNK
}

// ---------- fused h-gather + layer-2 transform: quarter-wave per node ----------
__global__ __launch_bounds__(256) void k_hgather(const int* __restrict__ offs, const int* __restrict__ hist,
                                                 const int* __restrict__ blkoff,
                                                 const int2* __restrict__ ei2, const ushort* __restrict__ Y,
                                                 const float* __restrict__ b1,
                                                 const float* __restrict__ W2, const float* __restrict__ Wr2,
                                                 float* __restrict__ t, int N) {
  __shared__ float Wt[18 * 128];
  int tid = threadIdx.x;
  for (int i = tid; i < 2304; i += 256) {
    float v; int oc, d;
    if (i < 2048) { int r = i >> 8, rem = i & 255; d = rem >> 1; int c = rem & 1; oc = r * 2 + c; v = W2[i]; }
    else { int i2 = i - 2048; d = i2 >> 1; int c = i2 & 1; oc = 16 + c; v = Wr2[i2]; }
    Wt[oc * 128 + d] = v;
  }
  __syncthreads();

  int node = blockIdx.x * 16 + (tid >> 4);
  int ql = tid & 15;
  if (node >= N) return;
  int c0 = ql * 8;
  int seg0 = node * NR;
  int bo = blkoff[seg0 >> 10];  // all 8 segs of a node share one 1024-block
  int st = offs[seg0] - hist[seg0] + bo;
  int en = offs[seg0 + 7] + bo;

  float a[8];
  {
    U128 vr;
    vr.u = *(const uint4*)(Y + (size_t)node * 1152 + 1024 + c0);
    float4 bb0 = *(const float4*)(b1 + c0);
    float4 bb1 = *(const float4*)(b1 + c0 + 4);
    a[0] = bf2f((ushort)vr.s[0]) + bb0.x;
    a[1] = bf2f((ushort)vr.s[1]) + bb0.y;
    a[2] = bf2f((ushort)vr.s[2]) + bb0.z;
    a[3] = bf2f((ushort)vr.s[3]) + bb0.w;
    a[4] = bf2f((ushort)vr.s[4]) + bb1.x;
    a[5] = bf2f((ushort)vr.s[5]) + bb1.y;
    a[6] = bf2f((ushort)vr.s[6]) + bb1.z;
    a[7] = bf2f((ushort)vr.s[7]) + bb1.w;
  }

  #define ACC8(V, SC)                                                          \
    {                                                                          \
      _Pragma("unroll")                                                        \
      for (int j = 0; j < 8; j++) a[j] += bf2f((ushort)(V).s[j]) * (SC);       \
    }

  int i = st;
  for (; i + 8 <= en; i += 8) {
    int2 e0 = ei2[i + 0];
    int2 e1 = ei2[i + 1];
    int2 e2 = ei2[i + 2];
    int2 e3 = ei2[i + 3];
    int2 e4 = ei2[i + 4];
    int2 e5 = ei2[i + 5];
    int2 e6 = ei2[i + 6];
    int2 e7 = ei2[i + 7];
    U128 v0, v1, v2, v3, v4, v5, v6, v7;
    v0.u = *(const uint4*)(Y + (((uint)(e0.x + (e0.x >> 3)) << 7) + c0));
    v1.u = *(const uint4*)(Y + (((uint)(e1.x + (e1.x >> 3)) << 7) + c0));
    v2.u = *(const uint4*)(Y + (((uint)(e2.x + (e2.x >> 3)) << 7) + c0));
    v3.u = *(const uint4*)(Y + (((uint)(e3.x + (e3.x >> 3)) << 7) + c0));
    v4.u = *(const uint4*)(Y + (((uint)(e4.x + (e4.x >> 3)) << 7) + c0));
    v5.u = *(const uint4*)(Y + (((uint)(e5.x + (e5.x >> 3)) << 7) + c0));
    v6.u = *(const uint4*)(Y + (((uint)(e6.x + (e6.x >> 3)) << 7) + c0));
    v7.u = *(const uint4*)(Y + (((uint)(e7.x + (e7.x >> 3)) << 7) + c0));
    FU s0, s1, s2, s3, s4, s5, s6, s7;
    s0.i = e0.y; s1.i = e1.y; s2.i = e2.y; s3.i = e3.y;
    s4.i = e4.y; s5.i = e5.y; s6.i = e6.y; s7.i = e7.y;
    ACC8(v0, s0.f); ACC8(v1, s1.f); ACC8(v2, s2.f); ACC8(v3, s3.f);
    ACC8(v4, s4.f); ACC8(v5, s5.f); ACC8(v6, s6.f); ACC8(v7, s7.f);
  }
  for (; i + 4 <= en; i += 4) {
    int2 e0 = ei2[i + 0];
    int2 e1 = ei2[i + 1];
    int2 e2 = ei2[i + 2];
    int2 e3 = ei2[i + 3];
    U128 v0, v1, v2, v3;
    v0.u = *(const uint4*)(Y + (((uint)(e0.x + (e0.x >> 3)) << 7) + c0));
    v1.u = *(const uint4*)(Y + (((uint)(e1.x + (e1.x >> 3)) << 7) + c0));
    v2.u = *(const uint4*)(Y + (((uint)(e2.x + (e2.x >> 3)) << 7) + c0));
    v3.u = *(const uint4*)(Y + (((uint)(e3.x + (e3.x >> 3)) << 7) + c0));
    FU s0, s1, s2, s3;
    s0.i = e0.y; s1.i = e1.y; s2.i = e2.y; s3.i = e3.y;
    ACC8(v0, s0.f); ACC8(v1, s1.f); ACC8(v2, s2.f); ACC8(v3, s3.f);
  }
  for (; i < en; i++) {
    int2 e = ei2[i];
    U128 v;
    v.u = *(const uint4*)(Y + (((uint)(e.x + (e.x >> 3)) << 7) + c0));
    FU sc; sc.i = e.y;
    ACC8(v, sc.f);
  }
  #undef ACC8

  float h[8];
  #pragma unroll
  for (int j = 0; j < 8; j++) h[j] = fmaxf(a[j], 0.f);

  #pragma unroll
  for (int oc = 0; oc < 18; oc++) {
    float4 wv0 = *(const float4*)(Wt + oc * 128 + c0);
    float4 wv1 = *(const float4*)(Wt + oc * 128 + c0 + 4);
    float p = h[0] * wv0.x + h[1] * wv0.y + h[2] * wv0.z + h[3] * wv0.w +
              h[4] * wv1.x + h[5] * wv1.y + h[6] * wv1.z + h[7] * wv1.w;
    p += __shfl_xor(p, 8);
    p += __shfl_xor(p, 4);
    p += __shfl_xor(p, 2);
    p += __shfl_xor(p, 1);
    if (ql == 0) t[(size_t)node * 18 + oc] = p;
  }
}

// ---------- output: 8 lanes per node (lane = relation), scale pre-folded ----------
__global__ __launch_bounds__(256) void k_out2(const int* __restrict__ offs, const int* __restrict__ hist,
                                              const int* __restrict__ blkoff,
                                              const int2* __restrict__ ei2, const float* __restrict__ t,
                                              const float* __restrict__ b2, float* __restrict__ out, int N) {
  int tid = threadIdx.x;
  int node = blockIdx.x * 32 + (tid >> 3);
  int r = tid & 7;
  if (node >= N) return;
  int seg = node * NR + r;
  int en = offs[seg] + blkoff[seg >> 10];
  int cc = hist[seg];
  float s0 = 0.f, s1 = 0.f;
  for (int i = en - cc; i < en; i++) {
    int2 e = ei2[i];
    int src = e.x >> 3;
    FU sc; sc.i = e.y;
    float2 tv = *(const float2*)(t + (size_t)src * 18 + r * 2);
    s0 += tv.x * sc.f;
    s1 += tv.y * sc.f;
  }
  s0 += __shfl_xor(s0, 1); s1 += __shfl_xor(s1, 1);
  s0 += __shfl_xor(s0, 2); s1 += __shfl_xor(s1, 2);
  s0 += __shfl_xor(s0, 4); s1 += __shfl_xor(s1, 4);
  if (r == 0) {
    out[(size_t)node * 2 + 0] = s0 + t[(size_t)node * 18 + 16] + b2[0];
    out[(size_t)node * 2 + 1] = s1 + t[(size_t)node * 18 + 17] + b2[1];
  }
}

extern "C" void kernel_launch(void* const* d_in, const int* in_sizes, int n_in,
                              void* d_out, int out_size, void* d_ws, size_t ws_size,
                              hipStream_t stream) {
  const float* x   = (const float*)d_in[0];
  const int*   ei  = (const int*)d_in[1];
  const int*   et  = (const int*)d_in[2];
  const float* W1  = (const float*)d_in[3];
  const float* Wr1 = (const float*)d_in[4];
  const float* b1  = (const float*)d_in[5];
  const float* W2  = (const float*)d_in[6];
  const float* Wr2 = (const float*)d_in[7];
  const float* b2  = (const float*)d_in[8];
  float* out = (float*)d_out;

  int E = in_sizes[1] / 2;
  int N = in_sizes[0] / DH;
  int S = N * NR;
  const int* src = ei;
  const int* dst = ei + E;

  // ws layout: ints | ei2 (int2, E) | WF (frag-major) | Y | t
  int* hist       = (int*)d_ws;                  // S
  int* offs       = hist + S;                    // S
  int* blksum     = offs + S;                    // 1024
  int* blkoff     = blksum + 1024;               // 1024
  int2* ei2       = (int2*)(blkoff + 1024);      // E int2 (8B-aligned)
  size_t int_elems = (size_t)S * 2 + 2048 + (size_t)E * 2;
  int_elems = (int_elems + 3) & ~(size_t)3;      // 16B align
  ushort* WF = (ushort*)(hist + int_elems);      // 2*1152*128
  ushort* Y  = WF + 2 * 1152 * 128;              // N*1152
  size_t ush_elems = 2 * 1152 * 128 + (size_t)N * 1152;
  ush_elems = (ush_elems + 1) & ~(size_t)1;      // float align
  float* t = (float*)(WF + ush_elems);           // N*18

  hipMemsetAsync(hist, 0, sizeof(int) * (size_t)S, stream);

  k_hist<<<(E + 255) / 256, 256, 0, stream>>>(dst, et, hist, E);

  int NB = (S + 1023) / 1024;
  k_scan_local<<<NB, 256, 0, stream>>>(hist, offs, blksum, S);
  k_scan_blk<<<1, 512, 0, stream>>>(blksum, blkoff, NB);

  k_scatter_idx<<<(E + 255) / 256, 256, 0, stream>>>(src, dst, et, hist, blkoff, offs, ei2, E);

  k_wsplit<<<72, 256, 0, stream>>>(W1, Wr1, WF);

  k_gemm_dense<<<(N + 63) / 64, 256, 0, stream>>>(x, WF, Y, N);

  k_hgather<<<(N + 15) / 16, 256, 0, stream>>>(offs, hist, blkoff, ei2, Y, b1, W2, Wr2, t, N);

  k_out2<<<(N + 31) / 32, 256, 0, stream>>>(offs, hist, blkoff, ei2, t, b2, out, N);
}